// Round 16
// baseline (590.325 us; speedup 1.0000x reference)
//
#include <hip/hip_runtime.h>
#include <math.h>

#define SM_EPS 1e-16f
#define LOG2E 1.4426950408889634f

typedef unsigned short u16;
typedef unsigned int u32;
typedef unsigned char u8;
typedef short s16x8 __attribute__((ext_vector_type(8)));
typedef float f32x4 __attribute__((ext_vector_type(4)));

__device__ __forceinline__ u16 f2bfh(float x) {
  __bf16 b = (__bf16)x;
  return __builtin_bit_cast(unsigned short, b);
}
__device__ __forceinline__ float bf2f(u16 u) {
  return __uint_as_float(((u32)u) << 16);
}
// e4m3 for POSITIVE in-range values only (ew = exp(logit) in [0.3, 3])
__device__ __forceinline__ u32 f2e4m3(float v) {
  const u32 b = __float_as_uint(v);
  const u32 m = b - 0x3C000000u;
  return (m + 0x7FFFFu + ((m >> 20) & 1u)) >> 20;  // RNE
}
__device__ __forceinline__ float e4m32f(u32 q) {
  return __uint_as_float(((q & 0x7Fu) << 20) + 0x3C000000u);
}

// -------- weight + epoi prep (once per call) --------
// Wb1/bb1 pre-scaled by log2e so the edge-MLP epilogue is a bare exp2.
__global__ __launch_bounds__(256) void k_prep(const float* __restrict__ Wa,
                                              const float* __restrict__ Wb,
                                              const float* __restrict__ Wc,
                                              const float* __restrict__ Wd,
                                              const float* __restrict__ W1,
                                              const float* __restrict__ Wa2,
                                              const float* __restrict__ Wb2,
                                              const float* __restrict__ Wc2,
                                              const float* __restrict__ Wd2,
                                              const float* __restrict__ bb2,
                                              const float* __restrict__ bd2,
                                              const float* __restrict__ bb1,
                                              const float* __restrict__ epoi,
                                              u16* __restrict__ WaTg, u16* __restrict__ WbTg,
                                              u16* __restrict__ WcTg, u16* __restrict__ WdTg,
                                              u16* __restrict__ W1Tg,
                                              u16* __restrict__ WaT2g, u16* __restrict__ WbT2g,
                                              u16* __restrict__ WcT2g, u16* __restrict__ WdT2g,
                                              float* __restrict__ bb48, float* __restrict__ bd48,
                                              float* __restrict__ bb1s,
                                              u16* __restrict__ epoiP,
                                              int N) {
  const int idx = blockIdx.x * 256 + threadIdx.x;
  if (idx < 2048) {
    const int n = idx >> 4, k = idx & 15;
    WaTg[idx] = f2bfh(Wa[k * 128 + n]);
  } else if (idx < 18432) {
    const int t = idx - 2048;
    const int n = t >> 7, k = t & 127;
    WbTg[t] = f2bfh(Wb[k * 128 + n] * LOG2E);   // pre-scaled for exp2
  } else if (idx < 20480) {
    const int t = idx - 18432;
    const int n = t >> 4, k = t & 15;
    WcTg[t] = f2bfh(Wc[k * 128 + n]);
  } else if (idx < 36864) {
    const int t = idx - 20480;
    const int n = t >> 7, k = t & 127;
    WdTg[t] = f2bfh(Wd[k * 128 + n]);
  } else if (idx < 102400) {
    const int t = idx - 36864;
    const int n = t >> 9, k = t & 511;
    W1Tg[t] = f2bfh(W1[k * 128 + n]);
  } else {
    const int t = idx - 102400;
    if (t < 768) {
      const int n = t >> 4, k = t & 15;
      WaT2g[t] = (n < 40) ? f2bfh(Wa2[k * 40 + n]) : (u16)0;
    } else if (t < 3840) {
      const int t2 = t - 768;
      const int n = t2 >> 6, k = t2 & 63;
      WbT2g[t2] = (n < 40 && k < 40) ? f2bfh(Wb2[k * 40 + n]) : (u16)0;
    } else if (t < 4608) {
      const int t2 = t - 3840;
      const int n = t2 >> 4, k = t2 & 15;
      WcT2g[t2] = (n < 40) ? f2bfh(Wc2[k * 40 + n]) : (u16)0;
    } else if (t < 7680) {
      const int t2 = t - 4608;
      const int n = t2 >> 6, k = t2 & 63;
      WdT2g[t2] = (n < 40 && k < 40) ? f2bfh(Wd2[k * 40 + n]) : (u16)0;
    } else if (t < 7728) {
      const int t2 = t - 7680;
      bb48[t2] = (t2 < 40) ? bb2[t2] : 0.f;
    } else if (t < 7776) {
      const int t2 = t - 7728;
      bd48[t2] = (t2 < 40) ? bd2[t2] : 0.f;
    } else if (t < 7904) {
      const int t2 = t - 7776;
      bb1s[t2] = bb1[t2] * LOG2E;               // pre-scaled for exp2
    } else {
      const int t3 = t - 7904;
      if (t3 < 2 * N) {
        const int r = t3 >> 1, half = t3 & 1;
        const float4 f0 = *reinterpret_cast<const float4*>(&epoi[(size_t)r * 16 + half * 8]);
        const float4 f1 = *reinterpret_cast<const float4*>(&epoi[(size_t)r * 16 + half * 8 + 4]);
        u32 pk[4];
        pk[0] = (u32)f2bfh(f0.x) | ((u32)f2bfh(f0.y) << 16);
        pk[1] = (u32)f2bfh(f0.z) | ((u32)f2bfh(f0.w) << 16);
        pk[2] = (u32)f2bfh(f1.x) | ((u32)f2bfh(f1.y) << 16);
        pk[3] = (u32)f2bfh(f1.z) | ((u32)f2bfh(f1.w) << 16);
        *reinterpret_cast<uint4*>(&epoiP[(size_t)r * 16 + half * 8]) = make_uint4(pk[0], pk[1], pk[2], pk[3]);
      }
    }
  }
}

// ---------------- h1 = x @ W1 via MFMA: [M,512]@[512,128], bf16 ----------------
__global__ __launch_bounds__(256) void k_gemm1m(const float* __restrict__ x,
                                                const u16* __restrict__ WT,  // [128][512]
                                                float* __restrict__ C, int M) {
  const int tid = threadIdx.x;
  const int lane = tid & 63;
  const int w = tid >> 6;
  const int wr = w >> 1, wc = w & 1;
  const int lg = lane >> 4;
  const int lm = lane & 15;
  const int r0 = blockIdx.x * 64;

  const f32x4 z4 = {0.f, 0.f, 0.f, 0.f};
  f32x4 acc[2][4];
#pragma unroll
  for (int i = 0; i < 2; ++i)
#pragma unroll
    for (int j = 0; j < 4; ++j) acc[i][j] = z4;

  auto load_chunk = [&](int ch, s16x8 af[2], s16x8 bf_[4]) {
#pragma unroll
    for (int i = 0; i < 2; ++i) {
      const int row = r0 + (wr * 2 + i) * 16 + lm;
      s16x8 a = (s16x8)0;
      if (row < M) {
        const float4 f0 = *reinterpret_cast<const float4*>(&x[(size_t)row * 512 + ch * 32 + lg * 8]);
        const float4 f1 = *reinterpret_cast<const float4*>(&x[(size_t)row * 512 + ch * 32 + lg * 8 + 4]);
        a[0] = (short)f2bfh(f0.x); a[1] = (short)f2bfh(f0.y);
        a[2] = (short)f2bfh(f0.z); a[3] = (short)f2bfh(f0.w);
        a[4] = (short)f2bfh(f1.x); a[5] = (short)f2bfh(f1.y);
        a[6] = (short)f2bfh(f1.z); a[7] = (short)f2bfh(f1.w);
      }
      af[i] = a;
    }
#pragma unroll
    for (int j = 0; j < 4; ++j) {
      const int n = (wc * 4 + j) * 16 + lm;
      bf_[j] = *reinterpret_cast<const s16x8*>(&WT[(size_t)n * 512 + ch * 32 + lg * 8]);
    }
  };

  s16x8 af[2], bf_[4];
  load_chunk(0, af, bf_);
  for (int ch = 0; ch < 16; ++ch) {
    s16x8 naf[2], nbf[4];
    if (ch < 15) load_chunk(ch + 1, naf, nbf);
#pragma unroll
    for (int i = 0; i < 2; ++i)
#pragma unroll
      for (int j = 0; j < 4; ++j)
        acc[i][j] = __builtin_amdgcn_mfma_f32_16x16x32_bf16(af[i], bf_[j], acc[i][j], 0, 0, 0);
    if (ch < 15) {
#pragma unroll
      for (int i = 0; i < 2; ++i) af[i] = naf[i];
#pragma unroll
      for (int j = 0; j < 4; ++j) bf_[j] = nbf[j];
    }
  }

#pragma unroll
  for (int i = 0; i < 2; ++i) {
#pragma unroll
    for (int rr = 0; rr < 4; ++rr) {
      const int row = r0 + (wr * 2 + i) * 16 + lg * 4 + rr;
      if (row < M) {
#pragma unroll
        for (int j = 0; j < 4; ++j)
          C[(size_t)row * 128 + (wc * 4 + j) * 16 + lm] = acc[i][j][rr];
      }
    }
  }
}

// ------- MFMA fused 16->128->128 MLP over bf16 rows -------
// 64 rows/block, 4 waves = 4 col-quadrants. 16KB LDS (stage1->2 transpose only).
// MODE 0: exp2 -> fp8 e4m3 DIRECT global byte stores (weights pre-scaled by log2e).
// MODE 1: lrelu(0.01) -> bf16 via LDS coalesced stores.
template <int MODE>
__global__ __launch_bounds__(256) void k_emlp(
    const u16* __restrict__ inp,              // [R][16] bf16
    const u16* __restrict__ WaTg, const u16* __restrict__ WbTg,
    const float* __restrict__ bbias,
    void* __restrict__ outp, int R) {
  __shared__ __align__(16) unsigned char sU[16384];
  const int tid = threadIdx.x;
  const int lane = tid & 63;
  const int wc = tid >> 6;   // 0..3 col quadrant
  const int lg = lane >> 4;
  const int lm = lane & 15;
  const int r0 = blockIdx.x * 64;

  s16x8 afr[4];
#pragma unroll
  for (int i = 0; i < 4; ++i) {
    s16x8 a = (s16x8)0;
    if (lg < 2) {
      const int r = r0 + i * 16 + lm;
      if (r < R) a = *reinterpret_cast<const s16x8*>(&inp[(size_t)r * 16 + lg * 8]);
    }
    afr[i] = a;
  }

  const f32x4 z4 = {0.f, 0.f, 0.f, 0.f};
  s16x8 bfr1[2];
#pragma unroll
  for (int j = 0; j < 2; ++j) {
    s16x8 b = (s16x8)0;
    if (lg < 2) {
      const int n = wc * 32 + j * 16 + lm;
      b = *reinterpret_cast<const s16x8*>(&WaTg[n * 16 + lg * 8]);
    }
    bfr1[j] = b;
  }

  f32x4 acc1[4][2];
#pragma unroll
  for (int i = 0; i < 4; ++i)
#pragma unroll
    for (int j = 0; j < 2; ++j) acc1[i][j] = z4;
#pragma unroll
  for (int i = 0; i < 4; ++i)
#pragma unroll
    for (int j = 0; j < 2; ++j)
      acc1[i][j] = __builtin_amdgcn_mfma_f32_16x16x32_bf16(afr[i], bfr1[j], acc1[i][j], 0, 0, 0);

#pragma unroll
  for (int i = 0; i < 4; ++i) {
#pragma unroll
    for (int j = 0; j < 2; ++j) {
#pragma unroll
      for (int rr = 0; rr < 4; ++rr) {
        float v = acc1[i][j][rr];
        v = (v >= 0.f) ? v : 0.2f * v;
        const int grow = i * 16 + lg * 4 + rr;
        const int gcol = wc * 32 + j * 16 + lm;
        const int byte = grow * 256 + ((((gcol >> 3) ^ (grow & 15))) << 4) + (gcol & 7) * 2;
        *reinterpret_cast<u16*>(&sU[byte]) = f2bfh(v);
      }
    }
  }
  __syncthreads();

  f32x4 acc[4][2];
#pragma unroll
  for (int i = 0; i < 4; ++i)
#pragma unroll
    for (int j = 0; j < 2; ++j) acc[i][j] = z4;
#pragma unroll
  for (int kb = 0; kb < 4; ++kb) {
    s16x8 af[4], bf_[2];
    const int ch = kb * 4 + lg;
#pragma unroll
    for (int j = 0; j < 2; ++j) {
      const int n = wc * 32 + j * 16 + lm;
      bf_[j] = *reinterpret_cast<const s16x8*>(&WbTg[n * 128 + ch * 8]);
    }
#pragma unroll
    for (int i = 0; i < 4; ++i) {
      const int row = i * 16 + lm;
      af[i] = *reinterpret_cast<const s16x8*>(&sU[row * 256 + ((ch ^ (row & 15)) << 4)]);
    }
#pragma unroll
    for (int i = 0; i < 4; ++i)
#pragma unroll
      for (int j = 0; j < 2; ++j)
        acc[i][j] = __builtin_amdgcn_mfma_f32_16x16x32_bf16(af[i], bf_[j], acc[i][j], 0, 0, 0);
  }

  float bv[2];
#pragma unroll
  for (int j = 0; j < 2; ++j) bv[j] = bbias[wc * 32 + j * 16 + lm];

  if (MODE == 0) {
    // direct global fp8 stores (logits already in log2 domain)
    u8* o8 = (u8*)outp;
#pragma unroll
    for (int i = 0; i < 4; ++i) {
#pragma unroll
      for (int rr = 0; rr < 4; ++rr) {
        const int grow = r0 + i * 16 + lg * 4 + rr;
        if (grow < R) {
#pragma unroll
          for (int j = 0; j < 2; ++j) {
            const float v = exp2f(acc[i][j][rr] + bv[j]);
            o8[(size_t)grow * 128 + wc * 32 + j * 16 + lm] = (u8)f2e4m3(v);
          }
        }
      }
    }
  } else {
    __syncthreads();  // done reading sU; safe to overwrite
#pragma unroll
    for (int i = 0; i < 4; ++i) {
#pragma unroll
      for (int j = 0; j < 2; ++j) {
#pragma unroll
        for (int rr = 0; rr < 4; ++rr) {
          float v = acc[i][j][rr] + bv[j];
          v = (v >= 0.f) ? v : 0.01f * v;
          const int grow = i * 16 + lg * 4 + rr;
          const int gcol = wc * 32 + j * 16 + lm;
          const int byte = grow * 256 + ((((gcol >> 3) ^ (grow & 15))) << 4) + (gcol & 7) * 2;
          *reinterpret_cast<u16*>(&sU[byte]) = f2bfh(v);
        }
      }
    }
    __syncthreads();
    u16* o16 = (u16*)outp;
    const int rmax = R - r0;
#pragma unroll
    for (int q = 0; q < 4; ++q) {
      const int u = tid + q * 256;
      const int row = u >> 4, c8 = u & 15;
      if (row < rmax) {
        const uint4 v = *reinterpret_cast<const uint4*>(&sU[row * 256 + ((c8 ^ (row & 15)) << 4)]);
        *reinterpret_cast<uint4*>(&o16[(size_t)(r0 + row) * 128 + c8 * 8]) = v;
      }
    }
  }
}

// ------- MFMA fused 16->40->40 MLP (48-padded), bf16 out -------
template <int MODE>
__global__ __launch_bounds__(256) void k_emlp48(
    const u16* __restrict__ inp,              // [R][16] bf16
    const u16* __restrict__ WaT,              // [48][16]
    const u16* __restrict__ WbT,              // [48][64]
    const float* __restrict__ bias48,         // [48]
    u16* __restrict__ outp, int R) {          // [R][40] bf16
  __shared__ __align__(16) unsigned char sU[16384];
  const int tid = threadIdx.x;
  const int lane = tid & 63;
  const int wv = tid >> 6;
  const int lg = lane >> 4;
  const int lm = lane & 15;
  const int r0 = blockIdx.x * 128;

#pragma unroll
  for (int q = 0; q < 4; ++q) {
    const int u = tid + q * 256;
    const int row = u >> 3;
    const int col = 48 + (u & 7) * 2;
    const int byte = row * 128 + ((((col >> 3) ^ (row & 7))) << 4) + (col & 7) * 2;
    *reinterpret_cast<u32*>(&sU[byte]) = 0;
  }

  s16x8 afr[2];
#pragma unroll
  for (int i = 0; i < 2; ++i) {
    s16x8 a = (s16x8)0;
    if (lg < 2) {
      const int r = r0 + wv * 32 + i * 16 + lm;
      if (r < R) a = *reinterpret_cast<const s16x8*>(&inp[(size_t)r * 16 + lg * 8]);
    }
    afr[i] = a;
  }
  const f32x4 z4 = {0.f, 0.f, 0.f, 0.f};
  s16x8 bfr1[3];
#pragma unroll
  for (int j = 0; j < 3; ++j) {
    s16x8 b = (s16x8)0;
    if (lg < 2) {
      const int n = j * 16 + lm;
      b = *reinterpret_cast<const s16x8*>(&WaT[n * 16 + lg * 8]);
    }
    bfr1[j] = b;
  }
  f32x4 acc1[2][3];
#pragma unroll
  for (int i = 0; i < 2; ++i)
#pragma unroll
    for (int j = 0; j < 3; ++j) acc1[i][j] = z4;
#pragma unroll
  for (int i = 0; i < 2; ++i)
#pragma unroll
    for (int j = 0; j < 3; ++j)
      acc1[i][j] = __builtin_amdgcn_mfma_f32_16x16x32_bf16(afr[i], bfr1[j], acc1[i][j], 0, 0, 0);

#pragma unroll
  for (int i = 0; i < 2; ++i) {
#pragma unroll
    for (int j = 0; j < 3; ++j) {
#pragma unroll
      for (int rr = 0; rr < 4; ++rr) {
        float v = acc1[i][j][rr];
        v = (v >= 0.f) ? v : 0.2f * v;
        const int grow = wv * 32 + i * 16 + lg * 4 + rr;
        const int gcol = j * 16 + lm;
        const int byte = grow * 128 + ((((gcol >> 3) ^ (grow & 7))) << 4) + (gcol & 7) * 2;
        *reinterpret_cast<u16*>(&sU[byte]) = f2bfh(v);
      }
    }
  }
  __syncthreads();

  f32x4 acc[2][3];
#pragma unroll
  for (int i = 0; i < 2; ++i)
#pragma unroll
    for (int j = 0; j < 3; ++j) acc[i][j] = z4;
#pragma unroll
  for (int kb = 0; kb < 2; ++kb) {
    s16x8 af[2], bf_[3];
    const int ch = kb * 4 + lg;
#pragma unroll
    for (int j = 0; j < 3; ++j) {
      const int n = j * 16 + lm;
      bf_[j] = *reinterpret_cast<const s16x8*>(&WbT[n * 64 + ch * 8]);
    }
#pragma unroll
    for (int i = 0; i < 2; ++i) {
      const int row = wv * 32 + i * 16 + lm;
      af[i] = *reinterpret_cast<const s16x8*>(&sU[row * 128 + ((ch ^ (row & 7)) << 4)]);
    }
#pragma unroll
    for (int i = 0; i < 2; ++i)
#pragma unroll
      for (int j = 0; j < 3; ++j)
        acc[i][j] = __builtin_amdgcn_mfma_f32_16x16x32_bf16(af[i], bf_[j], acc[i][j], 0, 0, 0);
  }
  __syncthreads();

  float bv[3];
#pragma unroll
  for (int j = 0; j < 3; ++j) bv[j] = bias48[j * 16 + lm];
#pragma unroll
  for (int i = 0; i < 2; ++i) {
#pragma unroll
    for (int j = 0; j < 3; ++j) {
#pragma unroll
      for (int rr = 0; rr < 4; ++rr) {
        float v = acc[i][j][rr] + bv[j];
        if (MODE == 0) v = __expf(v);
        else v = (v >= 0.f) ? v : 0.01f * v;
        const int grow = wv * 32 + i * 16 + lg * 4 + rr;
        const int gcol = j * 16 + lm;
        const int byte = grow * 128 + ((((gcol >> 3) ^ (grow & 7))) << 4) + (gcol & 7) * 2;
        *reinterpret_cast<u16*>(&sU[byte]) = f2bfh(v);
      }
    }
  }
  __syncthreads();

  const int rmax = R - r0;
  const int row = tid >> 1, half = tid & 1;
  if (row < rmax) {
    const size_t obase = (size_t)(r0 + row) * 40;
#pragma unroll
    for (int q = 0; q < 10; ++q) {
      const int col = (half * 10 + q) * 2;
      const int byte = row * 128 + ((((col >> 3) ^ (row & 7))) << 4) + (col & 7) * 2;
      *reinterpret_cast<u32*>(&outp[obase + col]) = *reinterpret_cast<const u32*>(&sU[byte]);
    }
  }
}

// ------------- h2 = y1 @ W2  [M,128]@[128,40] ----------
__global__ __launch_bounds__(256) void k_gemm2(const float* __restrict__ A,
                                               const float* __restrict__ B,
                                               float* __restrict__ C, int M) {
  __shared__ float Bs[128 * 40];
  const int tid = threadIdx.x;
  for (int i = tid; i < 5120; i += 256) Bs[i] = B[i];
  __syncthreads();
  const int r = blockIdx.x * 6 + tid / 40;
  const int c = tid % 40;
  if (tid >= 240 || r >= M) return;
  const float* arow = &A[(size_t)r * 128];
  float acc = 0.f;
#pragma unroll
  for (int k4 = 0; k4 < 32; ++k4) {
    const float4 av = *reinterpret_cast<const float4*>(&arow[k4 * 4]);
    acc = fmaf(av.x, Bs[(k4 * 4 + 0) * 40 + c], acc);
    acc = fmaf(av.y, Bs[(k4 * 4 + 1) * 40 + c], acc);
    acc = fmaf(av.z, Bs[(k4 * 4 + 2) * 40 + c], acc);
    acc = fmaf(av.w, Bs[(k4 * 4 + 3) * 40 + c], acc);
  }
  C[(size_t)r * 40 + c] = acc;
}

// ================= CSR build =================
__global__ __launch_bounds__(256) void k_hist(const int* __restrict__ src,
                                              const int* __restrict__ dst,
                                              int* __restrict__ cnt, int N, int E) {
  const int e = blockIdx.x * 256 + threadIdx.x;
  if (e >= E) return;
  atomicAdd(&cnt[src[e]], 1);
  atomicAdd(&cnt[N + dst[e]], 1);
}

__global__ __launch_bounds__(256) void k_scanA(const int* __restrict__ cnt,
                                               int* __restrict__ bsum, int N, int NB) {
  const int arr = blockIdx.x / NB, bb = blockIdx.x % NB;
  const int g = bb * 256 + threadIdx.x;
  int v = (g < N) ? cnt[arr * N + g] : 0;
  __shared__ int sd[256];
  sd[threadIdx.x] = v;
  __syncthreads();
  for (int off = 128; off > 0; off >>= 1) {
    if (threadIdx.x < off) sd[threadIdx.x] += sd[threadIdx.x + off];
    __syncthreads();
  }
  if (threadIdx.x == 0) bsum[arr * 256 + bb] = sd[0];
}

__global__ __launch_bounds__(256) void k_scanB(const int* __restrict__ bsum,
                                               int* __restrict__ boff, int NB) {
  __shared__ int sd[256];
  for (int arr = 0; arr < 2; ++arr) {
    const int v = (threadIdx.x < NB) ? bsum[arr * 256 + threadIdx.x] : 0;
    sd[threadIdx.x] = v;
    __syncthreads();
    for (int off = 1; off < 256; off <<= 1) {
      const int t = (threadIdx.x >= off) ? sd[threadIdx.x - off] : 0;
      __syncthreads();
      sd[threadIdx.x] += t;
      __syncthreads();
    }
    if (threadIdx.x < NB) boff[arr * 256 + threadIdx.x] = sd[threadIdx.x] - v;
    __syncthreads();
  }
}

__global__ __launch_bounds__(256) void k_scanC(const int* __restrict__ cnt,
                                               const int* __restrict__ boff,
                                               int* __restrict__ row_src,
                                               int* __restrict__ row_dst,
                                               int* __restrict__ cur, int N, int NB) {
  const int arr = blockIdx.x / NB, bb = blockIdx.x % NB;
  const int g = bb * 256 + threadIdx.x;
  const int v = (g < N) ? cnt[arr * N + g] : 0;
  __shared__ int sd[256];
  sd[threadIdx.x] = v;
  __syncthreads();
  for (int off = 1; off < 256; off <<= 1) {
    const int t = (threadIdx.x >= off) ? sd[threadIdx.x - off] : 0;
    __syncthreads();
    sd[threadIdx.x] += t;
    __syncthreads();
  }
  const int incl = sd[threadIdx.x];
  const int base = boff[arr * 256 + bb];
  int* row = arr ? row_dst : row_src;
  if (g < N) {
    row[g] = base + incl - v;
    cur[arr * N + g] = base + incl - v;
    if (g == N - 1) row[N] = base + incl;
  }
}

// per-edge: ps = src-order position, pd = dst-order position.
__global__ __launch_bounds__(256) void k_scatter(const int* __restrict__ src,
                                                 const int* __restrict__ dst,
                                                 int* __restrict__ cur,
                                                 const float* __restrict__ kric,
                                                 u16* __restrict__ kricP,
                                                 uint2* __restrict__ pdInfo, int N, int E) {
  const int e = blockIdx.x * 256 + threadIdx.x;
  if (e >= E) return;
  const int s = src[e], d = dst[e];
  const float4 f0 = *reinterpret_cast<const float4*>(&kric[(size_t)e * 16]);
  const float4 f1 = *reinterpret_cast<const float4*>(&kric[(size_t)e * 16 + 4]);
  const float4 f2 = *reinterpret_cast<const float4*>(&kric[(size_t)e * 16 + 8]);
  const float4 f3 = *reinterpret_cast<const float4*>(&kric[(size_t)e * 16 + 12]);
  const int ps = atomicAdd(&cur[s], 1);
  const int pd = atomicAdd(&cur[N + d], 1);
  pdInfo[pd] = make_uint2((u32)ps, (u32)s);
  u32 pk[8];
  pk[0] = (u32)f2bfh(f0.x) | ((u32)f2bfh(f0.y) << 16);
  pk[1] = (u32)f2bfh(f0.z) | ((u32)f2bfh(f0.w) << 16);
  pk[2] = (u32)f2bfh(f1.x) | ((u32)f2bfh(f1.y) << 16);
  pk[3] = (u32)f2bfh(f1.z) | ((u32)f2bfh(f1.w) << 16);
  pk[4] = (u32)f2bfh(f2.x) | ((u32)f2bfh(f2.y) << 16);
  pk[5] = (u32)f2bfh(f2.z) | ((u32)f2bfh(f2.w) << 16);
  pk[6] = (u32)f2bfh(f3.x) | ((u32)f2bfh(f3.y) << 16);
  pk[7] = (u32)f2bfh(f3.z) | ((u32)f2bfh(f3.w) << 16);
  u16* outr = &kricP[(size_t)ps * 16];
  *reinterpret_cast<uint4*>(outr) = make_uint4(pk[0], pk[1], pk[2], pk[3]);
  *reinterpret_cast<uint4*>(outr + 8) = make_uint4(pk[4], pk[5], pk[6], pk[7]);
}

// ===== layer1: s = segsum(fp8 ew rows [r0,r1)), gB = bf16(h/(s+eps)) =====
__global__ __launch_bounds__(256) void k_norm128f8(const int* __restrict__ rowp,
                                                   const u8* __restrict__ ew8,
                                                   const float* __restrict__ h,
                                                   u16* __restrict__ gB, int N) {
  const int lane = threadIdx.x & 63;
  const int wv = threadIdx.x >> 6;
  const int n = blockIdx.x * 4 + wv;
  if (n >= N) return;
  const int c0 = lane * 2;
  const int r0 = rowp[n], r1 = rowp[n + 1];
  float a0 = 0.f, a1 = 0.f;
  int p = r0;
  for (; p + 2 <= r1; p += 2) {
    const u32 w0 = *reinterpret_cast<const u16*>(&ew8[(size_t)p * 128 + c0]);
    const u32 w1 = *reinterpret_cast<const u16*>(&ew8[(size_t)(p + 1) * 128 + c0]);
    a0 += e4m32f(w0 & 0xffu) + e4m32f(w1 & 0xffu);
    a1 += e4m32f(w0 >> 8) + e4m32f(w1 >> 8);
  }
  for (; p < r1; ++p) {
    const u32 w0 = *reinterpret_cast<const u16*>(&ew8[(size_t)p * 128 + c0]);
    a0 += e4m32f(w0 & 0xffu);
    a1 += e4m32f(w0 >> 8);
  }
  const float2 hv = *reinterpret_cast<const float2*>(&h[(size_t)n * 128 + c0]);
  const float gx = hv.x / (a0 + SM_EPS);
  const float gy = hv.y / (a1 + SM_EPS);
  *reinterpret_cast<u32*>(&gB[(size_t)n * 128 + c0]) = (u32)f2bfh(gx) | ((u32)f2bfh(gy) << 16);
}

// ===== layer1 agg: out = sum ew8[pd.x]*gB[pd.y] + b + alpha*pw, ELU =====
__global__ __launch_bounds__(256) void k_aggf128f8(const int* __restrict__ rowp,
                                                   const uint2* __restrict__ pdInfo,
                                                   const u8* __restrict__ ew8,
                                                   const u16* __restrict__ gB,
                                                   const u16* __restrict__ pw,
                                                   const float* __restrict__ bias,
                                                   const float* __restrict__ alpha_p,
                                                   float* __restrict__ out, int N) {
  const int lane = threadIdx.x & 63;
  const int wv = threadIdx.x >> 6;
  const int n = blockIdx.x * 4 + wv;
  if (n >= N) return;
  const int c0 = lane * 2;
  const int r0 = rowp[n], r1 = rowp[n + 1];
  float a0 = 0.f, a1 = 0.f;
  int p = r0;
  for (; p + 8 <= r1; p += 8) {
    uint2 ii[8];
    u32 ww[8];
    u32 gg[8];
#pragma unroll
    for (int t = 0; t < 8; ++t) ii[t] = pdInfo[p + t];
#pragma unroll
    for (int t = 0; t < 8; ++t) ww[t] = *reinterpret_cast<const u16*>(&ew8[(size_t)ii[t].x * 128 + c0]);
#pragma unroll
    for (int t = 0; t < 8; ++t) gg[t] = *reinterpret_cast<const u32*>(&gB[(size_t)ii[t].y * 128 + c0]);
#pragma unroll
    for (int t = 0; t < 8; ++t) {
      a0 = fmaf(e4m32f(ww[t] & 0xffu), bf2f((u16)(gg[t] & 0xffffu)), a0);
      a1 = fmaf(e4m32f(ww[t] >> 8), bf2f((u16)(gg[t] >> 16)), a1);
    }
  }
  for (; p < r1; ++p) {
    const uint2 i0 = pdInfo[p];
    const u32 w0 = *reinterpret_cast<const u16*>(&ew8[(size_t)i0.x * 128 + c0]);
    const u32 g0 = *reinterpret_cast<const u32*>(&gB[(size_t)i0.y * 128 + c0]);
    a0 = fmaf(e4m32f(w0 & 0xffu), bf2f((u16)(g0 & 0xffffu)), a0);
    a1 = fmaf(e4m32f(w0 >> 8), bf2f((u16)(g0 >> 16)), a1);
  }
  const float al = alpha_p[0];
  const u32 pv2 = *reinterpret_cast<const u32*>(&pw[(size_t)n * 128 + c0]);
  float v0 = a0 + bias[c0] + al * bf2f((u16)(pv2 & 0xffffu));
  float v1 = a1 + bias[c0 + 1] + al * bf2f((u16)(pv2 >> 16));
  v0 = (v0 > 0.f) ? v0 : expm1f(v0);
  v1 = (v1 > 0.f) ? v1 : expm1f(v1);
  *reinterpret_cast<float2*>(&out[(size_t)n * 128 + c0]) = make_float2(v0, v1);
}

// ===== layer2 (bf16 ew, C=40): s = segsum, gB = bf16(h/(s+eps)) =====
__global__ __launch_bounds__(256) void k_norm40(const int* __restrict__ rowp,
                                                const u16* __restrict__ ew,
                                                const float* __restrict__ h,
                                                u16* __restrict__ gB, int N) {
  const int lane = threadIdx.x & 63;
  const int wv = threadIdx.x >> 6;
  const int n = blockIdx.x * 4 + wv;
  if (n >= N) return;
  const int c0 = lane;
  if (c0 >= 40) return;
  const int r0 = rowp[n], r1 = rowp[n + 1];
  float a0 = 0.f;
  int p = r0;
  for (; p + 2 <= r1; p += 2)
    a0 += bf2f(ew[(size_t)p * 40 + c0]) + bf2f(ew[(size_t)(p + 1) * 40 + c0]);
  for (; p < r1; ++p) a0 += bf2f(ew[(size_t)p * 40 + c0]);
  gB[(size_t)n * 40 + c0] = f2bfh(h[(size_t)n * 40 + c0] / (a0 + SM_EPS));
}

__global__ __launch_bounds__(256) void k_aggf40(const int* __restrict__ rowp,
                                                const uint2* __restrict__ pdInfo,
                                                const u16* __restrict__ ew,
                                                const u16* __restrict__ gB,
                                                const u16* __restrict__ pw,
                                                const float* __restrict__ bias,
                                                const float* __restrict__ alpha_p,
                                                float* __restrict__ out, int N) {
  const int lane = threadIdx.x & 63;
  const int wv = threadIdx.x >> 6;
  const int n = blockIdx.x * 4 + wv;
  if (n >= N) return;
  const int c0 = lane;
  if (c0 >= 40) return;
  const int r0 = rowp[n], r1 = rowp[n + 1];
  float a0 = 0.f;
  int p = r0;
  for (; p + 4 <= r1; p += 4) {
    const uint2 i0 = pdInfo[p + 0], i1 = pdInfo[p + 1], i2 = pdInfo[p + 2], i3 = pdInfo[p + 3];
    const float w0 = bf2f(ew[(size_t)i0.x * 40 + c0]);
    const float w1 = bf2f(ew[(size_t)i1.x * 40 + c0]);
    const float w2 = bf2f(ew[(size_t)i2.x * 40 + c0]);
    const float w3 = bf2f(ew[(size_t)i3.x * 40 + c0]);
    const float g0 = bf2f(gB[(size_t)i0.y * 40 + c0]);
    const float g1 = bf2f(gB[(size_t)i1.y * 40 + c0]);
    const float g2 = bf2f(gB[(size_t)i2.y * 40 + c0]);
    const float g3 = bf2f(gB[(size_t)i3.y * 40 + c0]);
    a0 = fmaf(w0, g0, a0);
    a0 = fmaf(w1, g1, a0);
    a0 = fmaf(w2, g2, a0);
    a0 = fmaf(w3, g3, a0);
  }
  for (; p < r1; ++p) {
    const uint2 i0 = pdInfo[p];
    a0 = fmaf(bf2f(ew[(size_t)i0.x * 40 + c0]), bf2f(gB[(size_t)i0.y * 40 + c0]), a0);
  }
  const float v = a0 + bias[c0] + alpha_p[0] * bf2f(pw[(size_t)n * 40 + c0]);
  out[(size_t)n * 40 + c0] = v;
}

extern "C" void kernel_launch(void* const* d_in, const int* in_sizes, int n_in,
                              void* d_out, int out_size, void* d_ws, size_t ws_size,
                              hipStream_t stream) {
  const float* x    = (const float*)d_in[0];
  const int*   ei   = (const int*)d_in[1];
  const float* kric = (const float*)d_in[2];
  const float* epoi = (const float*)d_in[3];
  const float* alpha= (const float*)d_in[4];
  const float* W1   = (const float*)d_in[5];
  const float* Wa1  = (const float*)d_in[6];
  const float* Wb1  = (const float*)d_in[7];
  const float* bb1  = (const float*)d_in[8];
  const float* Wc1  = (const float*)d_in[9];
  const float* Wd1  = (const float*)d_in[10];
  const float* bd1  = (const float*)d_in[11];
  const float* b1   = (const float*)d_in[12];
  const float* W2   = (const float*)d_in[13];
  const float* Wa2  = (const float*)d_in[14];
  const float* Wb2  = (const float*)d_in[15];
  const float* bb2  = (const float*)d_in[16];
  const float* Wc2  = (const float*)d_in[17];
  const float* Wd2  = (const float*)d_in[18];
  const float* bd2  = (const float*)d_in[19];
  const float* b2   = (const float*)d_in[20];

  const int N = in_sizes[0] / 512;
  const int E = in_sizes[1] / 2;
  const int* srcI = ei;
  const int* dstI = ei + E;
  const int NB = (N + 255) / 256;

  // ---- workspace layout ----
  char* p = (char*)d_ws;
  int* cnt      = (int*)p; p += (size_t)2 * N * 4;
  int* cur      = (int*)p; p += (size_t)2 * N * 4;
  int* bsum     = (int*)p; p += 512 * 4;
  int* boff     = (int*)p; p += 512 * 4;
  int* row_src  = (int*)p; p += (size_t)(N + 1) * 4;
  int* row_dst  = (int*)p; p += (size_t)(N + 1) * 4;
  p = (char*)(((uintptr_t)p + 255) & ~(uintptr_t)255);
  uint2* pdInfo = (uint2*)p; p += (size_t)E * 8;
  p = (char*)(((uintptr_t)p + 255) & ~(uintptr_t)255);
  u16* WaT1g = (u16*)p; p += 2048 * 2;
  u16* WbT1g = (u16*)p; p += 16384 * 2;
  u16* WcT1g = (u16*)p; p += 2048 * 2;
  u16* WdT1g = (u16*)p; p += 16384 * 2;
  u16* W1Tg  = (u16*)p; p += 65536 * 2;
  u16* WaT2g = (u16*)p; p += 768 * 2;
  u16* WbT2g = (u16*)p; p += 3072 * 2;
  u16* WcT2g = (u16*)p; p += 768 * 2;
  u16* WdT2g = (u16*)p; p += 3072 * 2;
  p = (char*)(((uintptr_t)p + 255) & ~(uintptr_t)255);
  float* bb48 = (float*)p; p += 48 * 4;
  float* bd48 = (float*)p; p += 48 * 4;
  float* bb1s = (float*)p; p += 128 * 4;
  p = (char*)(((uintptr_t)p + 255) & ~(uintptr_t)255);
  u16* kricP = (u16*)p; p += (size_t)E * 16 * 2;   // bf16, src-CSR order
  u16* epoiP = (u16*)p; p += (size_t)N * 16 * 2;   // bf16
  p = (char*)(((uintptr_t)p + 255) & ~(uintptr_t)255);
  float* h1  = (float*)p; p += (size_t)N * 128 * 4;
  u16* g1B   = (u16*)p;  p += (size_t)N * 128 * 2;   // bf16 normalized h1
  float* y1  = (float*)p; p += (size_t)N * 128 * 4;
  float* h2  = (float*)p; p += (size_t)N * 40 * 4;
  u16* g2B   = (u16*)p;  p += (size_t)N * 40 * 2;    // bf16 normalized h2
  u16* pw1   = (u16*)p;  p += (size_t)N * 128 * 2;   // bf16
  u16* pw2   = (u16*)p;  p += (size_t)N * 40 * 2;    // bf16
  p = (char*)(((uintptr_t)p + 255) & ~(uintptr_t)255);
  u8* ew8    = (u8*)p;   // layer1: E*128 fp8; layer2 reuses as E*40 bf16
  u16* ew40  = (u16*)p;

  // ---- CSR build + weight/input prep ----
  hipMemsetAsync(cnt, 0, (size_t)2 * N * 4, stream);
  k_prep<<<(110304 + 2 * N + 255) / 256, 256, 0, stream>>>(
      Wa1, Wb1, Wc1, Wd1, W1, Wa2, Wb2, Wc2, Wd2, bb2, bd2, bb1, epoi,
      WaT1g, WbT1g, WcT1g, WdT1g, W1Tg, WaT2g, WbT2g, WcT2g, WdT2g, bb48, bd48, bb1s, epoiP, N);
  k_hist<<<(E + 255) / 256, 256, 0, stream>>>(srcI, dstI, cnt, N, E);
  k_scanA<<<2 * NB, 256, 0, stream>>>(cnt, bsum, N, NB);
  k_scanB<<<1, 256, 0, stream>>>(bsum, boff, NB);
  k_scanC<<<2 * NB, 256, 0, stream>>>(cnt, boff, row_src, row_dst, cur, N, NB);
  k_scatter<<<(E + 255) / 256, 256, 0, stream>>>(srcI, dstI, cur, kric, kricP, pdInfo, N, E);

  // ---------------- layer 1 ----------------
  k_gemm1m<<<(N + 63) / 64, 256, 0, stream>>>(x, W1Tg, h1, N);
  k_emlp<0><<<(E + 63) / 64, 256, 0, stream>>>(kricP, WaT1g, WbT1g, bb1s, (void*)ew8, E);
  k_emlp<1><<<(N + 63) / 64, 256, 0, stream>>>(epoiP, WcT1g, WdT1g, bd1, (void*)pw1, N);
  k_norm128f8<<<(N + 3) / 4, 256, 0, stream>>>(row_src, ew8, h1, g1B, N);
  k_aggf128f8<<<(N + 3) / 4, 256, 0, stream>>>(row_dst, pdInfo, ew8, g1B, pw1, b1, alpha, y1, N);

  // ---------------- layer 2 ----------------
  k_gemm2<<<(N + 5) / 6, 256, 0, stream>>>(y1, W2, h2, N);
  k_emlp48<0><<<(E + 127) / 128, 256, 0, stream>>>(kricP, WaT2g, WbT2g, bb48, ew40, E);
  k_emlp48<1><<<(N + 127) / 128, 256, 0, stream>>>(epoiP, WcT2g, WdT2g, bd48, pw2, N);
  k_norm40<<<(N + 3) / 4, 256, 0, stream>>>(row_src, ew40, h2, g2B, N);
  k_aggf40<<<(N + 3) / 4, 256, 0, stream>>>(row_dst, pdInfo, ew40, g2B, pw2, b2, alpha, (float*)d_out, N);
}

// Round 17
// 582.561 us; speedup vs baseline: 1.0133x; 1.0133x over previous
//
#include <hip/hip_runtime.h>
#include <math.h>

#define SM_EPS 1e-16f
#define LOG2E 1.4426950408889634f

typedef unsigned short u16;
typedef unsigned int u32;
typedef unsigned char u8;
typedef short s16x8 __attribute__((ext_vector_type(8)));
typedef float f32x4 __attribute__((ext_vector_type(4)));

__device__ __forceinline__ u16 f2bfh(float x) {
  __bf16 b = (__bf16)x;
  return __builtin_bit_cast(unsigned short, b);
}
__device__ __forceinline__ float bf2f(u16 u) {
  return __uint_as_float(((u32)u) << 16);
}
// e4m3 for POSITIVE in-range values only (ew = exp(logit) in [0.3, 3])
__device__ __forceinline__ u32 f2e4m3(float v) {
  const u32 b = __float_as_uint(v);
  const u32 m = b - 0x3C000000u;
  return (m + 0x7FFFFu + ((m >> 20) & 1u)) >> 20;  // RNE
}
__device__ __forceinline__ float e4m32f(u32 q) {
  return __uint_as_float(((q & 0x7Fu) << 20) + 0x3C000000u);
}

// -------- weight + epoi prep (once per call) --------
// Wb1/bb1 pre-scaled by log2e so the edge-MLP epilogue is a bare exp2.
__global__ __launch_bounds__(256) void k_prep(const float* __restrict__ Wa,
                                              const float* __restrict__ Wb,
                                              const float* __restrict__ Wc,
                                              const float* __restrict__ Wd,
                                              const float* __restrict__ W1,
                                              const float* __restrict__ Wa2,
                                              const float* __restrict__ Wb2,
                                              const float* __restrict__ Wc2,
                                              const float* __restrict__ Wd2,
                                              const float* __restrict__ bb2,
                                              const float* __restrict__ bd2,
                                              const float* __restrict__ bb1,
                                              const float* __restrict__ epoi,
                                              u16* __restrict__ WaTg, u16* __restrict__ WbTg,
                                              u16* __restrict__ WcTg, u16* __restrict__ WdTg,
                                              u16* __restrict__ W1Tg,
                                              u16* __restrict__ WaT2g, u16* __restrict__ WbT2g,
                                              u16* __restrict__ WcT2g, u16* __restrict__ WdT2g,
                                              float* __restrict__ bb48, float* __restrict__ bd48,
                                              float* __restrict__ bb1s,
                                              u16* __restrict__ epoiP,
                                              int N) {
  const int idx = blockIdx.x * 256 + threadIdx.x;
  if (idx < 2048) {
    const int n = idx >> 4, k = idx & 15;
    WaTg[idx] = f2bfh(Wa[k * 128 + n]);
  } else if (idx < 18432) {
    const int t = idx - 2048;
    const int n = t >> 7, k = t & 127;
    WbTg[t] = f2bfh(Wb[k * 128 + n] * LOG2E);   // pre-scaled for exp2
  } else if (idx < 20480) {
    const int t = idx - 18432;
    const int n = t >> 4, k = t & 15;
    WcTg[t] = f2bfh(Wc[k * 128 + n]);
  } else if (idx < 36864) {
    const int t = idx - 20480;
    const int n = t >> 7, k = t & 127;
    WdTg[t] = f2bfh(Wd[k * 128 + n]);
  } else if (idx < 102400) {
    const int t = idx - 36864;
    const int n = t >> 9, k = t & 511;
    W1Tg[t] = f2bfh(W1[k * 128 + n]);
  } else {
    const int t = idx - 102400;
    if (t < 768) {
      const int n = t >> 4, k = t & 15;
      WaT2g[t] = (n < 40) ? f2bfh(Wa2[k * 40 + n]) : (u16)0;
    } else if (t < 3840) {
      const int t2 = t - 768;
      const int n = t2 >> 6, k = t2 & 63;
      WbT2g[t2] = (n < 40 && k < 40) ? f2bfh(Wb2[k * 40 + n]) : (u16)0;
    } else if (t < 4608) {
      const int t2 = t - 3840;
      const int n = t2 >> 4, k = t2 & 15;
      WcT2g[t2] = (n < 40) ? f2bfh(Wc2[k * 40 + n]) : (u16)0;
    } else if (t < 7680) {
      const int t2 = t - 4608;
      const int n = t2 >> 6, k = t2 & 63;
      WdT2g[t2] = (n < 40 && k < 40) ? f2bfh(Wd2[k * 40 + n]) : (u16)0;
    } else if (t < 7728) {
      const int t2 = t - 7680;
      bb48[t2] = (t2 < 40) ? bb2[t2] : 0.f;
    } else if (t < 7776) {
      const int t2 = t - 7728;
      bd48[t2] = (t2 < 40) ? bd2[t2] : 0.f;
    } else if (t < 7904) {
      const int t2 = t - 7776;
      bb1s[t2] = bb1[t2] * LOG2E;               // pre-scaled for exp2
    } else {
      const int t3 = t - 7904;
      if (t3 < 2 * N) {
        const int r = t3 >> 1, half = t3 & 1;
        const float4 f0 = *reinterpret_cast<const float4*>(&epoi[(size_t)r * 16 + half * 8]);
        const float4 f1 = *reinterpret_cast<const float4*>(&epoi[(size_t)r * 16 + half * 8 + 4]);
        u32 pk[4];
        pk[0] = (u32)f2bfh(f0.x) | ((u32)f2bfh(f0.y) << 16);
        pk[1] = (u32)f2bfh(f0.z) | ((u32)f2bfh(f0.w) << 16);
        pk[2] = (u32)f2bfh(f1.x) | ((u32)f2bfh(f1.y) << 16);
        pk[3] = (u32)f2bfh(f1.z) | ((u32)f2bfh(f1.w) << 16);
        *reinterpret_cast<uint4*>(&epoiP[(size_t)r * 16 + half * 8]) = make_uint4(pk[0], pk[1], pk[2], pk[3]);
      }
    }
  }
}

// ---------------- h1 = x @ W1 via MFMA: [M,512]@[512,128], bf16 ----------------
__global__ __launch_bounds__(256) void k_gemm1m(const float* __restrict__ x,
                                                const u16* __restrict__ WT,  // [128][512]
                                                float* __restrict__ C, int M) {
  const int tid = threadIdx.x;
  const int lane = tid & 63;
  const int w = tid >> 6;
  const int wr = w >> 1, wc = w & 1;
  const int lg = lane >> 4;
  const int lm = lane & 15;
  const int r0 = blockIdx.x * 64;

  const f32x4 z4 = {0.f, 0.f, 0.f, 0.f};
  f32x4 acc[2][4];
#pragma unroll
  for (int i = 0; i < 2; ++i)
#pragma unroll
    for (int j = 0; j < 4; ++j) acc[i][j] = z4;

  auto load_chunk = [&](int ch, s16x8 af[2], s16x8 bf_[4]) {
#pragma unroll
    for (int i = 0; i < 2; ++i) {
      const int row = r0 + (wr * 2 + i) * 16 + lm;
      s16x8 a = (s16x8)0;
      if (row < M) {
        const float4 f0 = *reinterpret_cast<const float4*>(&x[(size_t)row * 512 + ch * 32 + lg * 8]);
        const float4 f1 = *reinterpret_cast<const float4*>(&x[(size_t)row * 512 + ch * 32 + lg * 8 + 4]);
        a[0] = (short)f2bfh(f0.x); a[1] = (short)f2bfh(f0.y);
        a[2] = (short)f2bfh(f0.z); a[3] = (short)f2bfh(f0.w);
        a[4] = (short)f2bfh(f1.x); a[5] = (short)f2bfh(f1.y);
        a[6] = (short)f2bfh(f1.z); a[7] = (short)f2bfh(f1.w);
      }
      af[i] = a;
    }
#pragma unroll
    for (int j = 0; j < 4; ++j) {
      const int n = (wc * 4 + j) * 16 + lm;
      bf_[j] = *reinterpret_cast<const s16x8*>(&WT[(size_t)n * 512 + ch * 32 + lg * 8]);
    }
  };

  s16x8 af[2], bf_[4];
  load_chunk(0, af, bf_);
  for (int ch = 0; ch < 16; ++ch) {
    s16x8 naf[2], nbf[4];
    if (ch < 15) load_chunk(ch + 1, naf, nbf);
#pragma unroll
    for (int i = 0; i < 2; ++i)
#pragma unroll
      for (int j = 0; j < 4; ++j)
        acc[i][j] = __builtin_amdgcn_mfma_f32_16x16x32_bf16(af[i], bf_[j], acc[i][j], 0, 0, 0);
    if (ch < 15) {
#pragma unroll
      for (int i = 0; i < 2; ++i) af[i] = naf[i];
#pragma unroll
      for (int j = 0; j < 4; ++j) bf_[j] = nbf[j];
    }
  }

#pragma unroll
  for (int i = 0; i < 2; ++i) {
#pragma unroll
    for (int rr = 0; rr < 4; ++rr) {
      const int row = r0 + (wr * 2 + i) * 16 + lg * 4 + rr;
      if (row < M) {
#pragma unroll
        for (int j = 0; j < 4; ++j)
          C[(size_t)row * 128 + (wc * 4 + j) * 16 + lm] = acc[i][j][rr];
      }
    }
  }
}

// ------- MFMA fused 16->128->128 MLP over bf16 rows -------
// 64 rows/block, 4 waves = 4 col-quadrants. 16KB LDS.
// MODE 0: exp2 -> fp8 code in u16 LDS slot (conflict-free swizzle) -> packed uint2 stores.
// MODE 1: lrelu(0.01) -> bf16 via LDS coalesced stores.
template <int MODE>
__global__ __launch_bounds__(256) void k_emlp(
    const u16* __restrict__ inp,              // [R][16] bf16
    const u16* __restrict__ WaTg, const u16* __restrict__ WbTg,
    const float* __restrict__ bbias,
    void* __restrict__ outp, int R) {
  __shared__ __align__(16) unsigned char sU[16384];
  const int tid = threadIdx.x;
  const int lane = tid & 63;
  const int wc = tid >> 6;   // 0..3 col quadrant
  const int lg = lane >> 4;
  const int lm = lane & 15;
  const int r0 = blockIdx.x * 64;

  s16x8 afr[4];
#pragma unroll
  for (int i = 0; i < 4; ++i) {
    s16x8 a = (s16x8)0;
    if (lg < 2) {
      const int r = r0 + i * 16 + lm;
      if (r < R) a = *reinterpret_cast<const s16x8*>(&inp[(size_t)r * 16 + lg * 8]);
    }
    afr[i] = a;
  }

  const f32x4 z4 = {0.f, 0.f, 0.f, 0.f};
  s16x8 bfr1[2];
#pragma unroll
  for (int j = 0; j < 2; ++j) {
    s16x8 b = (s16x8)0;
    if (lg < 2) {
      const int n = wc * 32 + j * 16 + lm;
      b = *reinterpret_cast<const s16x8*>(&WaTg[n * 16 + lg * 8]);
    }
    bfr1[j] = b;
  }

  f32x4 acc1[4][2];
#pragma unroll
  for (int i = 0; i < 4; ++i)
#pragma unroll
    for (int j = 0; j < 2; ++j) acc1[i][j] = z4;
#pragma unroll
  for (int i = 0; i < 4; ++i)
#pragma unroll
    for (int j = 0; j < 2; ++j)
      acc1[i][j] = __builtin_amdgcn_mfma_f32_16x16x32_bf16(afr[i], bfr1[j], acc1[i][j], 0, 0, 0);

#pragma unroll
  for (int i = 0; i < 4; ++i) {
#pragma unroll
    for (int j = 0; j < 2; ++j) {
#pragma unroll
      for (int rr = 0; rr < 4; ++rr) {
        float v = acc1[i][j][rr];
        v = (v >= 0.f) ? v : 0.2f * v;
        const int grow = i * 16 + lg * 4 + rr;
        const int gcol = wc * 32 + j * 16 + lm;
        const int byte = grow * 256 + ((((gcol >> 3) ^ (grow & 15))) << 4) + (gcol & 7) * 2;
        *reinterpret_cast<u16*>(&sU[byte]) = f2bfh(v);
      }
    }
  }
  __syncthreads();

  f32x4 acc[4][2];
#pragma unroll
  for (int i = 0; i < 4; ++i)
#pragma unroll
    for (int j = 0; j < 2; ++j) acc[i][j] = z4;
#pragma unroll
  for (int kb = 0; kb < 4; ++kb) {
    s16x8 af[4], bf_[2];
    const int ch = kb * 4 + lg;
#pragma unroll
    for (int j = 0; j < 2; ++j) {
      const int n = wc * 32 + j * 16 + lm;
      bf_[j] = *reinterpret_cast<const s16x8*>(&WbTg[n * 128 + ch * 8]);
    }
#pragma unroll
    for (int i = 0; i < 4; ++i) {
      const int row = i * 16 + lm;
      af[i] = *reinterpret_cast<const s16x8*>(&sU[row * 256 + ((ch ^ (row & 15)) << 4)]);
    }
#pragma unroll
    for (int i = 0; i < 4; ++i)
#pragma unroll
      for (int j = 0; j < 2; ++j)
        acc[i][j] = __builtin_amdgcn_mfma_f32_16x16x32_bf16(af[i], bf_[j], acc[i][j], 0, 0, 0);
  }
  __syncthreads();  // done reading sU; safe to overwrite

  float bv[2];
#pragma unroll
  for (int j = 0; j < 2; ++j) bv[j] = bbias[wc * 32 + j * 16 + lm];

  if (MODE == 0) {
    // fp8 code stored in u16 slot via the conflict-free MODE-1 swizzle
#pragma unroll
    for (int i = 0; i < 4; ++i) {
#pragma unroll
      for (int j = 0; j < 2; ++j) {
#pragma unroll
        for (int rr = 0; rr < 4; ++rr) {
          const float v = exp2f(acc[i][j][rr] + bv[j]);
          const int grow = i * 16 + lg * 4 + rr;
          const int gcol = wc * 32 + j * 16 + lm;
          const int byte = grow * 256 + ((((gcol >> 3) ^ (grow & 15))) << 4) + (gcol & 7) * 2;
          *reinterpret_cast<u16*>(&sU[byte]) = (u16)f2e4m3(v);
        }
      }
    }
    __syncthreads();
    // copy-out: read 8 u16 codes, pack 8 bytes, one uint2 store
    u8* o8 = (u8*)outp;
    const int rmax = R - r0;
#pragma unroll
    for (int q = 0; q < 4; ++q) {
      const int u = tid + q * 256;
      const int row = u >> 4, c8 = u & 15;
      if (row < rmax) {
        const uint4 v = *reinterpret_cast<const uint4*>(&sU[row * 256 + ((c8 ^ (row & 15)) << 4)]);
        const u32 lo = (v.x & 0xffu) | ((v.x >> 8) & 0xff00u) |
                       ((v.y << 16) & 0xff0000u) | ((v.y << 8) & 0xff000000u);
        const u32 hi = (v.z & 0xffu) | ((v.z >> 8) & 0xff00u) |
                       ((v.w << 16) & 0xff0000u) | ((v.w << 8) & 0xff000000u);
        *reinterpret_cast<uint2*>(&o8[(size_t)(r0 + row) * 128 + c8 * 8]) = make_uint2(lo, hi);
      }
    }
  } else {
#pragma unroll
    for (int i = 0; i < 4; ++i) {
#pragma unroll
      for (int j = 0; j < 2; ++j) {
#pragma unroll
        for (int rr = 0; rr < 4; ++rr) {
          float v = acc[i][j][rr] + bv[j];
          v = (v >= 0.f) ? v : 0.01f * v;
          const int grow = i * 16 + lg * 4 + rr;
          const int gcol = wc * 32 + j * 16 + lm;
          const int byte = grow * 256 + ((((gcol >> 3) ^ (grow & 15))) << 4) + (gcol & 7) * 2;
          *reinterpret_cast<u16*>(&sU[byte]) = f2bfh(v);
        }
      }
    }
    __syncthreads();
    u16* o16 = (u16*)outp;
    const int rmax = R - r0;
#pragma unroll
    for (int q = 0; q < 4; ++q) {
      const int u = tid + q * 256;
      const int row = u >> 4, c8 = u & 15;
      if (row < rmax) {
        const uint4 v = *reinterpret_cast<const uint4*>(&sU[row * 256 + ((c8 ^ (row & 15)) << 4)]);
        *reinterpret_cast<uint4*>(&o16[(size_t)(r0 + row) * 128 + c8 * 8]) = v;
      }
    }
  }
}

// ------- MFMA fused 16->40->40 MLP (48-padded), bf16 out -------
template <int MODE>
__global__ __launch_bounds__(256) void k_emlp48(
    const u16* __restrict__ inp,              // [R][16] bf16
    const u16* __restrict__ WaT,              // [48][16]
    const u16* __restrict__ WbT,              // [48][64]
    const float* __restrict__ bias48,         // [48]
    u16* __restrict__ outp, int R) {          // [R][40] bf16
  __shared__ __align__(16) unsigned char sU[16384];
  const int tid = threadIdx.x;
  const int lane = tid & 63;
  const int wv = tid >> 6;
  const int lg = lane >> 4;
  const int lm = lane & 15;
  const int r0 = blockIdx.x * 128;

#pragma unroll
  for (int q = 0; q < 4; ++q) {
    const int u = tid + q * 256;
    const int row = u >> 3;
    const int col = 48 + (u & 7) * 2;
    const int byte = row * 128 + ((((col >> 3) ^ (row & 7))) << 4) + (col & 7) * 2;
    *reinterpret_cast<u32*>(&sU[byte]) = 0;
  }

  s16x8 afr[2];
#pragma unroll
  for (int i = 0; i < 2; ++i) {
    s16x8 a = (s16x8)0;
    if (lg < 2) {
      const int r = r0 + wv * 32 + i * 16 + lm;
      if (r < R) a = *reinterpret_cast<const s16x8*>(&inp[(size_t)r * 16 + lg * 8]);
    }
    afr[i] = a;
  }
  const f32x4 z4 = {0.f, 0.f, 0.f, 0.f};
  s16x8 bfr1[3];
#pragma unroll
  for (int j = 0; j < 3; ++j) {
    s16x8 b = (s16x8)0;
    if (lg < 2) {
      const int n = j * 16 + lm;
      b = *reinterpret_cast<const s16x8*>(&WaT[n * 16 + lg * 8]);
    }
    bfr1[j] = b;
  }
  f32x4 acc1[2][3];
#pragma unroll
  for (int i = 0; i < 2; ++i)
#pragma unroll
    for (int j = 0; j < 3; ++j) acc1[i][j] = z4;
#pragma unroll
  for (int i = 0; i < 2; ++i)
#pragma unroll
    for (int j = 0; j < 3; ++j)
      acc1[i][j] = __builtin_amdgcn_mfma_f32_16x16x32_bf16(afr[i], bfr1[j], acc1[i][j], 0, 0, 0);

#pragma unroll
  for (int i = 0; i < 2; ++i) {
#pragma unroll
    for (int j = 0; j < 3; ++j) {
#pragma unroll
      for (int rr = 0; rr < 4; ++rr) {
        float v = acc1[i][j][rr];
        v = (v >= 0.f) ? v : 0.2f * v;
        const int grow = wv * 32 + i * 16 + lg * 4 + rr;
        const int gcol = j * 16 + lm;
        const int byte = grow * 128 + ((((gcol >> 3) ^ (grow & 7))) << 4) + (gcol & 7) * 2;
        *reinterpret_cast<u16*>(&sU[byte]) = f2bfh(v);
      }
    }
  }
  __syncthreads();

  f32x4 acc[2][3];
#pragma unroll
  for (int i = 0; i < 2; ++i)
#pragma unroll
    for (int j = 0; j < 3; ++j) acc[i][j] = z4;
#pragma unroll
  for (int kb = 0; kb < 2; ++kb) {
    s16x8 af[2], bf_[3];
    const int ch = kb * 4 + lg;
#pragma unroll
    for (int j = 0; j < 3; ++j) {
      const int n = j * 16 + lm;
      bf_[j] = *reinterpret_cast<const s16x8*>(&WbT[n * 64 + ch * 8]);
    }
#pragma unroll
    for (int i = 0; i < 2; ++i) {
      const int row = wv * 32 + i * 16 + lm;
      af[i] = *reinterpret_cast<const s16x8*>(&sU[row * 128 + ((ch ^ (row & 7)) << 4)]);
    }
#pragma unroll
    for (int i = 0; i < 2; ++i)
#pragma unroll
      for (int j = 0; j < 3; ++j)
        acc[i][j] = __builtin_amdgcn_mfma_f32_16x16x32_bf16(af[i], bf_[j], acc[i][j], 0, 0, 0);
  }
  __syncthreads();

  float bv[3];
#pragma unroll
  for (int j = 0; j < 3; ++j) bv[j] = bias48[j * 16 + lm];
#pragma unroll
  for (int i = 0; i < 2; ++i) {
#pragma unroll
    for (int j = 0; j < 3; ++j) {
#pragma unroll
      for (int rr = 0; rr < 4; ++rr) {
        float v = acc[i][j][rr] + bv[j];
        if (MODE == 0) v = __expf(v);
        else v = (v >= 0.f) ? v : 0.01f * v;
        const int grow = wv * 32 + i * 16 + lg * 4 + rr;
        const int gcol = j * 16 + lm;
        const int byte = grow * 128 + ((((gcol >> 3) ^ (grow & 7))) << 4) + (gcol & 7) * 2;
        *reinterpret_cast<u16*>(&sU[byte]) = f2bfh(v);
      }
    }
  }
  __syncthreads();

  const int rmax = R - r0;
  const int row = tid >> 1, half = tid & 1;
  if (row < rmax) {
    const size_t obase = (size_t)(r0 + row) * 40;
#pragma unroll
    for (int q = 0; q < 10; ++q) {
      const int col = (half * 10 + q) * 2;
      const int byte = row * 128 + ((((col >> 3) ^ (row & 7))) << 4) + (col & 7) * 2;
      *reinterpret_cast<u32*>(&outp[obase + col]) = *reinterpret_cast<const u32*>(&sU[byte]);
    }
  }
}

// ------------- h2 = y1 @ W2  [M,128]@[128,40] ----------
__global__ __launch_bounds__(256) void k_gemm2(const float* __restrict__ A,
                                               const float* __restrict__ B,
                                               float* __restrict__ C, int M) {
  __shared__ float Bs[128 * 40];
  const int tid = threadIdx.x;
  for (int i = tid; i < 5120; i += 256) Bs[i] = B[i];
  __syncthreads();
  const int r = blockIdx.x * 6 + tid / 40;
  const int c = tid % 40;
  if (tid >= 240 || r >= M) return;
  const float* arow = &A[(size_t)r * 128];
  float acc = 0.f;
#pragma unroll
  for (int k4 = 0; k4 < 32; ++k4) {
    const float4 av = *reinterpret_cast<const float4*>(&arow[k4 * 4]);
    acc = fmaf(av.x, Bs[(k4 * 4 + 0) * 40 + c], acc);
    acc = fmaf(av.y, Bs[(k4 * 4 + 1) * 40 + c], acc);
    acc = fmaf(av.z, Bs[(k4 * 4 + 2) * 40 + c], acc);
    acc = fmaf(av.w, Bs[(k4 * 4 + 3) * 40 + c], acc);
  }
  C[(size_t)r * 40 + c] = acc;
}

// ================= CSR build =================
__global__ __launch_bounds__(256) void k_hist(const int* __restrict__ src,
                                              const int* __restrict__ dst,
                                              int* __restrict__ cnt, int N, int E) {
  const int e = blockIdx.x * 256 + threadIdx.x;
  if (e >= E) return;
  atomicAdd(&cnt[src[e]], 1);
  atomicAdd(&cnt[N + dst[e]], 1);
}

__global__ __launch_bounds__(256) void k_scanA(const int* __restrict__ cnt,
                                               int* __restrict__ bsum, int N, int NB) {
  const int arr = blockIdx.x / NB, bb = blockIdx.x % NB;
  const int g = bb * 256 + threadIdx.x;
  int v = (g < N) ? cnt[arr * N + g] : 0;
  __shared__ int sd[256];
  sd[threadIdx.x] = v;
  __syncthreads();
  for (int off = 128; off > 0; off >>= 1) {
    if (threadIdx.x < off) sd[threadIdx.x] += sd[threadIdx.x + off];
    __syncthreads();
  }
  if (threadIdx.x == 0) bsum[arr * 256 + bb] = sd[0];
}

__global__ __launch_bounds__(256) void k_scanB(const int* __restrict__ bsum,
                                               int* __restrict__ boff, int NB) {
  __shared__ int sd[256];
  for (int arr = 0; arr < 2; ++arr) {
    const int v = (threadIdx.x < NB) ? bsum[arr * 256 + threadIdx.x] : 0;
    sd[threadIdx.x] = v;
    __syncthreads();
    for (int off = 1; off < 256; off <<= 1) {
      const int t = (threadIdx.x >= off) ? sd[threadIdx.x - off] : 0;
      __syncthreads();
      sd[threadIdx.x] += t;
      __syncthreads();
    }
    if (threadIdx.x < NB) boff[arr * 256 + threadIdx.x] = sd[threadIdx.x] - v;
    __syncthreads();
  }
}

__global__ __launch_bounds__(256) void k_scanC(const int* __restrict__ cnt,
                                               const int* __restrict__ boff,
                                               int* __restrict__ row_src,
                                               int* __restrict__ row_dst,
                                               int* __restrict__ cur, int N, int NB) {
  const int arr = blockIdx.x / NB, bb = blockIdx.x % NB;
  const int g = bb * 256 + threadIdx.x;
  const int v = (g < N) ? cnt[arr * N + g] : 0;
  __shared__ int sd[256];
  sd[threadIdx.x] = v;
  __syncthreads();
  for (int off = 1; off < 256; off <<= 1) {
    const int t = (threadIdx.x >= off) ? sd[threadIdx.x - off] : 0;
    __syncthreads();
    sd[threadIdx.x] += t;
    __syncthreads();
  }
  const int incl = sd[threadIdx.x];
  const int base = boff[arr * 256 + bb];
  int* row = arr ? row_dst : row_src;
  if (g < N) {
    row[g] = base + incl - v;
    cur[arr * N + g] = base + incl - v;
    if (g == N - 1) row[N] = base + incl;
  }
}

// per-edge: ps = src-order position, pd = dst-order position.
__global__ __launch_bounds__(256) void k_scatter(const int* __restrict__ src,
                                                 const int* __restrict__ dst,
                                                 int* __restrict__ cur,
                                                 const float* __restrict__ kric,
                                                 u16* __restrict__ kricP,
                                                 uint2* __restrict__ pdInfo, int N, int E) {
  const int e = blockIdx.x * 256 + threadIdx.x;
  if (e >= E) return;
  const int s = src[e], d = dst[e];
  const float4 f0 = *reinterpret_cast<const float4*>(&kric[(size_t)e * 16]);
  const float4 f1 = *reinterpret_cast<const float4*>(&kric[(size_t)e * 16 + 4]);
  const float4 f2 = *reinterpret_cast<const float4*>(&kric[(size_t)e * 16 + 8]);
  const float4 f3 = *reinterpret_cast<const float4*>(&kric[(size_t)e * 16 + 12]);
  const int ps = atomicAdd(&cur[s], 1);
  const int pd = atomicAdd(&cur[N + d], 1);
  pdInfo[pd] = make_uint2((u32)ps, (u32)s);
  u32 pk[8];
  pk[0] = (u32)f2bfh(f0.x) | ((u32)f2bfh(f0.y) << 16);
  pk[1] = (u32)f2bfh(f0.z) | ((u32)f2bfh(f0.w) << 16);
  pk[2] = (u32)f2bfh(f1.x) | ((u32)f2bfh(f1.y) << 16);
  pk[3] = (u32)f2bfh(f1.z) | ((u32)f2bfh(f1.w) << 16);
  pk[4] = (u32)f2bfh(f2.x) | ((u32)f2bfh(f2.y) << 16);
  pk[5] = (u32)f2bfh(f2.z) | ((u32)f2bfh(f2.w) << 16);
  pk[6] = (u32)f2bfh(f3.x) | ((u32)f2bfh(f3.y) << 16);
  pk[7] = (u32)f2bfh(f3.z) | ((u32)f2bfh(f3.w) << 16);
  u16* outr = &kricP[(size_t)ps * 16];
  *reinterpret_cast<uint4*>(outr) = make_uint4(pk[0], pk[1], pk[2], pk[3]);
  *reinterpret_cast<uint4*>(outr + 8) = make_uint4(pk[4], pk[5], pk[6], pk[7]);
}

// ===== layer1: s = segsum(fp8 ew rows [r0,r1)), gB = bf16(h/(s+eps)) =====
__global__ __launch_bounds__(256) void k_norm128f8(const int* __restrict__ rowp,
                                                   const u8* __restrict__ ew8,
                                                   const float* __restrict__ h,
                                                   u16* __restrict__ gB, int N) {
  const int lane = threadIdx.x & 63;
  const int wv = threadIdx.x >> 6;
  const int n = blockIdx.x * 4 + wv;
  if (n >= N) return;
  const int c0 = lane * 2;
  const int r0 = rowp[n], r1 = rowp[n + 1];
  float a0 = 0.f, a1 = 0.f;
  int p = r0;
  for (; p + 2 <= r1; p += 2) {
    const u32 w0 = *reinterpret_cast<const u16*>(&ew8[(size_t)p * 128 + c0]);
    const u32 w1 = *reinterpret_cast<const u16*>(&ew8[(size_t)(p + 1) * 128 + c0]);
    a0 += e4m32f(w0 & 0xffu) + e4m32f(w1 & 0xffu);
    a1 += e4m32f(w0 >> 8) + e4m32f(w1 >> 8);
  }
  for (; p < r1; ++p) {
    const u32 w0 = *reinterpret_cast<const u16*>(&ew8[(size_t)p * 128 + c0]);
    a0 += e4m32f(w0 & 0xffu);
    a1 += e4m32f(w0 >> 8);
  }
  const float2 hv = *reinterpret_cast<const float2*>(&h[(size_t)n * 128 + c0]);
  const float gx = hv.x / (a0 + SM_EPS);
  const float gy = hv.y / (a1 + SM_EPS);
  *reinterpret_cast<u32*>(&gB[(size_t)n * 128 + c0]) = (u32)f2bfh(gx) | ((u32)f2bfh(gy) << 16);
}

// ===== layer1 agg: out = sum ew8[pd.x]*gB[pd.y] + b + alpha*pw, ELU =====
__global__ __launch_bounds__(256) void k_aggf128f8(const int* __restrict__ rowp,
                                                   const uint2* __restrict__ pdInfo,
                                                   const u8* __restrict__ ew8,
                                                   const u16* __restrict__ gB,
                                                   const u16* __restrict__ pw,
                                                   const float* __restrict__ bias,
                                                   const float* __restrict__ alpha_p,
                                                   float* __restrict__ out, int N) {
  const int lane = threadIdx.x & 63;
  const int wv = threadIdx.x >> 6;
  const int n = blockIdx.x * 4 + wv;
  if (n >= N) return;
  const int c0 = lane * 2;
  const int r0 = rowp[n], r1 = rowp[n + 1];
  float a0 = 0.f, a1 = 0.f;
  int p = r0;
  for (; p + 8 <= r1; p += 8) {
    uint2 ii[8];
    u32 ww[8];
    u32 gg[8];
#pragma unroll
    for (int t = 0; t < 8; ++t) ii[t] = pdInfo[p + t];
#pragma unroll
    for (int t = 0; t < 8; ++t) ww[t] = *reinterpret_cast<const u16*>(&ew8[(size_t)ii[t].x * 128 + c0]);
#pragma unroll
    for (int t = 0; t < 8; ++t) gg[t] = *reinterpret_cast<const u32*>(&gB[(size_t)ii[t].y * 128 + c0]);
#pragma unroll
    for (int t = 0; t < 8; ++t) {
      a0 = fmaf(e4m32f(ww[t] & 0xffu), bf2f((u16)(gg[t] & 0xffffu)), a0);
      a1 = fmaf(e4m32f(ww[t] >> 8), bf2f((u16)(gg[t] >> 16)), a1);
    }
  }
  for (; p < r1; ++p) {
    const uint2 i0 = pdInfo[p];
    const u32 w0 = *reinterpret_cast<const u16*>(&ew8[(size_t)i0.x * 128 + c0]);
    const u32 g0 = *reinterpret_cast<const u32*>(&gB[(size_t)i0.y * 128 + c0]);
    a0 = fmaf(e4m32f(w0 & 0xffu), bf2f((u16)(g0 & 0xffffu)), a0);
    a1 = fmaf(e4m32f(w0 >> 8), bf2f((u16)(g0 >> 16)), a1);
  }
  const float al = alpha_p[0];
  const u32 pv2 = *reinterpret_cast<const u32*>(&pw[(size_t)n * 128 + c0]);
  float v0 = a0 + bias[c0] + al * bf2f((u16)(pv2 & 0xffffu));
  float v1 = a1 + bias[c0 + 1] + al * bf2f((u16)(pv2 >> 16));
  v0 = (v0 > 0.f) ? v0 : expm1f(v0);
  v1 = (v1 > 0.f) ? v1 : expm1f(v1);
  *reinterpret_cast<float2*>(&out[(size_t)n * 128 + c0]) = make_float2(v0, v1);
}

// ===== layer2 (bf16 ew, C=40): s = segsum, gB = bf16(h/(s+eps)) =====
__global__ __launch_bounds__(256) void k_norm40(const int* __restrict__ rowp,
                                                const u16* __restrict__ ew,
                                                const float* __restrict__ h,
                                                u16* __restrict__ gB, int N) {
  const int lane = threadIdx.x & 63;
  const int wv = threadIdx.x >> 6;
  const int n = blockIdx.x * 4 + wv;
  if (n >= N) return;
  const int c0 = lane;
  if (c0 >= 40) return;
  const int r0 = rowp[n], r1 = rowp[n + 1];
  float a0 = 0.f;
  int p = r0;
  for (; p + 2 <= r1; p += 2)
    a0 += bf2f(ew[(size_t)p * 40 + c0]) + bf2f(ew[(size_t)(p + 1) * 40 + c0]);
  for (; p < r1; ++p) a0 += bf2f(ew[(size_t)p * 40 + c0]);
  gB[(size_t)n * 40 + c0] = f2bfh(h[(size_t)n * 40 + c0] / (a0 + SM_EPS));
}

__global__ __launch_bounds__(256) void k_aggf40(const int* __restrict__ rowp,
                                                const uint2* __restrict__ pdInfo,
                                                const u16* __restrict__ ew,
                                                const u16* __restrict__ gB,
                                                const u16* __restrict__ pw,
                                                const float* __restrict__ bias,
                                                const float* __restrict__ alpha_p,
                                                float* __restrict__ out, int N) {
  const int lane = threadIdx.x & 63;
  const int wv = threadIdx.x >> 6;
  const int n = blockIdx.x * 4 + wv;
  if (n >= N) return;
  const int c0 = lane;
  if (c0 >= 40) return;
  const int r0 = rowp[n], r1 = rowp[n + 1];
  float a0 = 0.f;
  int p = r0;
  for (; p + 4 <= r1; p += 4) {
    const uint2 i0 = pdInfo[p + 0], i1 = pdInfo[p + 1], i2 = pdInfo[p + 2], i3 = pdInfo[p + 3];
    const float w0 = bf2f(ew[(size_t)i0.x * 40 + c0]);
    const float w1 = bf2f(ew[(size_t)i1.x * 40 + c0]);
    const float w2 = bf2f(ew[(size_t)i2.x * 40 + c0]);
    const float w3 = bf2f(ew[(size_t)i3.x * 40 + c0]);
    const float g0 = bf2f(gB[(size_t)i0.y * 40 + c0]);
    const float g1 = bf2f(gB[(size_t)i1.y * 40 + c0]);
    const float g2 = bf2f(gB[(size_t)i2.y * 40 + c0]);
    const float g3 = bf2f(gB[(size_t)i3.y * 40 + c0]);
    a0 = fmaf(w0, g0, a0);
    a0 = fmaf(w1, g1, a0);
    a0 = fmaf(w2, g2, a0);
    a0 = fmaf(w3, g3, a0);
  }
  for (; p < r1; ++p) {
    const uint2 i0 = pdInfo[p];
    a0 = fmaf(bf2f(ew[(size_t)i0.x * 40 + c0]), bf2f(gB[(size_t)i0.y * 40 + c0]), a0);
  }
  const float v = a0 + bias[c0] + alpha_p[0] * bf2f(pw[(size_t)n * 40 + c0]);
  out[(size_t)n * 40 + c0] = v;
}

extern "C" void kernel_launch(void* const* d_in, const int* in_sizes, int n_in,
                              void* d_out, int out_size, void* d_ws, size_t ws_size,
                              hipStream_t stream) {
  const float* x    = (const float*)d_in[0];
  const int*   ei   = (const int*)d_in[1];
  const float* kric = (const float*)d_in[2];
  const float* epoi = (const float*)d_in[3];
  const float* alpha= (const float*)d_in[4];
  const float* W1   = (const float*)d_in[5];
  const float* Wa1  = (const float*)d_in[6];
  const float* Wb1  = (const float*)d_in[7];
  const float* bb1  = (const float*)d_in[8];
  const float* Wc1  = (const float*)d_in[9];
  const float* Wd1  = (const float*)d_in[10];
  const float* bd1  = (const float*)d_in[11];
  const float* b1   = (const float*)d_in[12];
  const float* W2   = (const float*)d_in[13];
  const float* Wa2  = (const float*)d_in[14];
  const float* Wb2  = (const float*)d_in[15];
  const float* bb2  = (const float*)d_in[16];
  const float* Wc2  = (const float*)d_in[17];
  const float* Wd2  = (const float*)d_in[18];
  const float* bd2  = (const float*)d_in[19];
  const float* b2   = (const float*)d_in[20];

  const int N = in_sizes[0] / 512;
  const int E = in_sizes[1] / 2;
  const int* srcI = ei;
  const int* dstI = ei + E;
  const int NB = (N + 255) / 256;

  // ---- workspace layout ----
  char* p = (char*)d_ws;
  int* cnt      = (int*)p; p += (size_t)2 * N * 4;
  int* cur      = (int*)p; p += (size_t)2 * N * 4;
  int* bsum     = (int*)p; p += 512 * 4;
  int* boff     = (int*)p; p += 512 * 4;
  int* row_src  = (int*)p; p += (size_t)(N + 1) * 4;
  int* row_dst  = (int*)p; p += (size_t)(N + 1) * 4;
  p = (char*)(((uintptr_t)p + 255) & ~(uintptr_t)255);
  uint2* pdInfo = (uint2*)p; p += (size_t)E * 8;
  p = (char*)(((uintptr_t)p + 255) & ~(uintptr_t)255);
  u16* WaT1g = (u16*)p; p += 2048 * 2;
  u16* WbT1g = (u16*)p; p += 16384 * 2;
  u16* WcT1g = (u16*)p; p += 2048 * 2;
  u16* WdT1g = (u16*)p; p += 16384 * 2;
  u16* W1Tg  = (u16*)p; p += 65536 * 2;
  u16* WaT2g = (u16*)p; p += 768 * 2;
  u16* WbT2g = (u16*)p; p += 3072 * 2;
  u16* WcT2g = (u16*)p; p += 768 * 2;
  u16* WdT2g = (u16*)p; p += 3072 * 2;
  p = (char*)(((uintptr_t)p + 255) & ~(uintptr_t)255);
  float* bb48 = (float*)p; p += 48 * 4;
  float* bd48 = (float*)p; p += 48 * 4;
  float* bb1s = (float*)p; p += 128 * 4;
  p = (char*)(((uintptr_t)p + 255) & ~(uintptr_t)255);
  u16* kricP = (u16*)p; p += (size_t)E * 16 * 2;   // bf16, src-CSR order
  u16* epoiP = (u16*)p; p += (size_t)N * 16 * 2;   // bf16
  p = (char*)(((uintptr_t)p + 255) & ~(uintptr_t)255);
  float* h1  = (float*)p; p += (size_t)N * 128 * 4;
  u16* g1B   = (u16*)p;  p += (size_t)N * 128 * 2;   // bf16 normalized h1
  float* y1  = (float*)p; p += (size_t)N * 128 * 4;
  float* h2  = (float*)p; p += (size_t)N * 40 * 4;
  u16* g2B   = (u16*)p;  p += (size_t)N * 40 * 2;    // bf16 normalized h2
  u16* pw1   = (u16*)p;  p += (size_t)N * 128 * 2;   // bf16
  u16* pw2   = (u16*)p;  p += (size_t)N * 40 * 2;    // bf16
  p = (char*)(((uintptr_t)p + 255) & ~(uintptr_t)255);
  u8* ew8    = (u8*)p;   // layer1: E*128 fp8; layer2 reuses as E*40 bf16
  u16* ew40  = (u16*)p;

  // ---- CSR build + weight/input prep ----
  hipMemsetAsync(cnt, 0, (size_t)2 * N * 4, stream);
  k_prep<<<(110304 + 2 * N + 255) / 256, 256, 0, stream>>>(
      Wa1, Wb1, Wc1, Wd1, W1, Wa2, Wb2, Wc2, Wd2, bb2, bd2, bb1, epoi,
      WaT1g, WbT1g, WcT1g, WdT1g, W1Tg, WaT2g, WbT2g, WcT2g, WdT2g, bb48, bd48, bb1s, epoiP, N);
  k_hist<<<(E + 255) / 256, 256, 0, stream>>>(srcI, dstI, cnt, N, E);
  k_scanA<<<2 * NB, 256, 0, stream>>>(cnt, bsum, N, NB);
  k_scanB<<<1, 256, 0, stream>>>(bsum, boff, NB);
  k_scanC<<<2 * NB, 256, 0, stream>>>(cnt, boff, row_src, row_dst, cur, N, NB);
  k_scatter<<<(E + 255) / 256, 256, 0, stream>>>(srcI, dstI, cur, kric, kricP, pdInfo, N, E);

  // ---------------- layer 1 ----------------
  k_gemm1m<<<(N + 63) / 64, 256, 0, stream>>>(x, W1Tg, h1, N);
  k_emlp<0><<<(E + 63) / 64, 256, 0, stream>>>(kricP, WaT1g, WbT1g, bb1s, (void*)ew8, E);
  k_emlp<1><<<(N + 63) / 64, 256, 0, stream>>>(epoiP, WcT1g, WdT1g, bd1, (void*)pw1, N);
  k_norm128f8<<<(N + 3) / 4, 256, 0, stream>>>(row_src, ew8, h1, g1B, N);
  k_aggf128f8<<<(N + 3) / 4, 256, 0, stream>>>(row_dst, pdInfo, ew8, g1B, pw1, b1, alpha, y1, N);

  // ---------------- layer 2 ----------------
  k_gemm2<<<(N + 5) / 6, 256, 0, stream>>>(y1, W2, h2, N);
  k_emlp48<0><<<(E + 127) / 128, 256, 0, stream>>>(kricP, WaT2g, WbT2g, bb48, ew40, E);
  k_emlp48<1><<<(N + 127) / 128, 256, 0, stream>>>(epoiP, WcT2g, WdT2g, bd48, pw2, N);
  k_norm40<<<(N + 3) / 4, 256, 0, stream>>>(row_src, ew40, h2, g2B, N);
  k_aggf40<<<(N + 3) / 4, 256, 0, stream>>>(row_dst, pdInfo, ew40, g2B, pw2, b2, alpha, (float*)d_out, N);
}

// Round 18
// 578.725 us; speedup vs baseline: 1.0200x; 1.0066x over previous
//
#include <hip/hip_runtime.h>
#include <math.h>

#define SM_EPS 1e-16f
#define LOG2E 1.4426950408889634f

typedef unsigned short u16;
typedef unsigned int u32;
typedef unsigned char u8;
typedef short s16x8 __attribute__((ext_vector_type(8)));
typedef float f32x4 __attribute__((ext_vector_type(4)));

__device__ __forceinline__ u16 f2bfh(float x) {
  __bf16 b = (__bf16)x;
  return __builtin_bit_cast(unsigned short, b);
}
__device__ __forceinline__ float bf2f(u16 u) {
  return __uint_as_float(((u32)u) << 16);
}
// e4m3 for POSITIVE in-range values only (ew = exp(logit) in [0.3, 3])
__device__ __forceinline__ u32 f2e4m3(float v) {
  const u32 b = __float_as_uint(v);
  const u32 m = b - 0x3C000000u;
  return (m + 0x7FFFFu + ((m >> 20) & 1u)) >> 20;  // RNE
}
// encode a pair of positive in-range f32 -> 2 packed e4m3 bytes (low 16 bits)
__device__ __forceinline__ u32 f2e4m3_pair(float a, float b) {
#if __has_builtin(__builtin_amdgcn_cvt_pk_fp8_f32)
  return (u32)__builtin_amdgcn_cvt_pk_fp8_f32(a, b, 0, false) & 0xffffu;
#else
  return f2e4m3(a) | (f2e4m3(b) << 8);
#endif
}
__device__ __forceinline__ float e4m32f(u32 q) {
  return __uint_as_float(((q & 0x7Fu) << 20) + 0x3C000000u);
}

// -------- weight + epoi prep (once per call) --------
// Wb1/bb1 pre-scaled by log2e so the edge-MLP epilogue is a bare exp2.
__global__ __launch_bounds__(256) void k_prep(const float* __restrict__ Wa,
                                              const float* __restrict__ Wb,
                                              const float* __restrict__ Wc,
                                              const float* __restrict__ Wd,
                                              const float* __restrict__ W1,
                                              const float* __restrict__ Wa2,
                                              const float* __restrict__ Wb2,
                                              const float* __restrict__ Wc2,
                                              const float* __restrict__ Wd2,
                                              const float* __restrict__ bb2,
                                              const float* __restrict__ bd2,
                                              const float* __restrict__ bb1,
                                              const float* __restrict__ epoi,
                                              u16* __restrict__ WaTg, u16* __restrict__ WbTg,
                                              u16* __restrict__ WcTg, u16* __restrict__ WdTg,
                                              u16* __restrict__ W1Tg,
                                              u16* __restrict__ WaT2g, u16* __restrict__ WbT2g,
                                              u16* __restrict__ WcT2g, u16* __restrict__ WdT2g,
                                              float* __restrict__ bb48, float* __restrict__ bd48,
                                              float* __restrict__ bb1s,
                                              u16* __restrict__ epoiP,
                                              int N) {
  const int idx = blockIdx.x * 256 + threadIdx.x;
  if (idx < 2048) {
    const int n = idx >> 4, k = idx & 15;
    WaTg[idx] = f2bfh(Wa[k * 128 + n]);
  } else if (idx < 18432) {
    const int t = idx - 2048;
    const int n = t >> 7, k = t & 127;
    WbTg[t] = f2bfh(Wb[k * 128 + n] * LOG2E);   // pre-scaled for exp2
  } else if (idx < 20480) {
    const int t = idx - 18432;
    const int n = t >> 4, k = t & 15;
    WcTg[t] = f2bfh(Wc[k * 128 + n]);
  } else if (idx < 36864) {
    const int t = idx - 20480;
    const int n = t >> 7, k = t & 127;
    WdTg[t] = f2bfh(Wd[k * 128 + n]);
  } else if (idx < 102400) {
    const int t = idx - 36864;
    const int n = t >> 9, k = t & 511;
    W1Tg[t] = f2bfh(W1[k * 128 + n]);
  } else {
    const int t = idx - 102400;
    if (t < 768) {
      const int n = t >> 4, k = t & 15;
      WaT2g[t] = (n < 40) ? f2bfh(Wa2[k * 40 + n]) : (u16)0;
    } else if (t < 3840) {
      const int t2 = t - 768;
      const int n = t2 >> 6, k = t2 & 63;
      WbT2g[t2] = (n < 40 && k < 40) ? f2bfh(Wb2[k * 40 + n]) : (u16)0;
    } else if (t < 4608) {
      const int t2 = t - 3840;
      const int n = t2 >> 4, k = t2 & 15;
      WcT2g[t2] = (n < 40) ? f2bfh(Wc2[k * 40 + n]) : (u16)0;
    } else if (t < 7680) {
      const int t2 = t - 4608;
      const int n = t2 >> 6, k = t2 & 63;
      WdT2g[t2] = (n < 40 && k < 40) ? f2bfh(Wd2[k * 40 + n]) : (u16)0;
    } else if (t < 7728) {
      const int t2 = t - 7680;
      bb48[t2] = (t2 < 40) ? bb2[t2] : 0.f;
    } else if (t < 7776) {
      const int t2 = t - 7728;
      bd48[t2] = (t2 < 40) ? bd2[t2] : 0.f;
    } else if (t < 7904) {
      const int t2 = t - 7776;
      bb1s[t2] = bb1[t2] * LOG2E;               // pre-scaled for exp2
    } else {
      const int t3 = t - 7904;
      if (t3 < 2 * N) {
        const int r = t3 >> 1, half = t3 & 1;
        const float4 f0 = *reinterpret_cast<const float4*>(&epoi[(size_t)r * 16 + half * 8]);
        const float4 f1 = *reinterpret_cast<const float4*>(&epoi[(size_t)r * 16 + half * 8 + 4]);
        u32 pk[4];
        pk[0] = (u32)f2bfh(f0.x) | ((u32)f2bfh(f0.y) << 16);
        pk[1] = (u32)f2bfh(f0.z) | ((u32)f2bfh(f0.w) << 16);
        pk[2] = (u32)f2bfh(f1.x) | ((u32)f2bfh(f1.y) << 16);
        pk[3] = (u32)f2bfh(f1.z) | ((u32)f2bfh(f1.w) << 16);
        *reinterpret_cast<uint4*>(&epoiP[(size_t)r * 16 + half * 8]) = make_uint4(pk[0], pk[1], pk[2], pk[3]);
      }
    }
  }
}

// ---------------- h1 = x @ W1 via MFMA: [M,512]@[512,128], bf16 ----------------
__global__ __launch_bounds__(256) void k_gemm1m(const float* __restrict__ x,
                                                const u16* __restrict__ WT,  // [128][512]
                                                float* __restrict__ C, int M) {
  const int tid = threadIdx.x;
  const int lane = tid & 63;
  const int w = tid >> 6;
  const int wr = w >> 1, wc = w & 1;
  const int lg = lane >> 4;
  const int lm = lane & 15;
  const int r0 = blockIdx.x * 64;

  const f32x4 z4 = {0.f, 0.f, 0.f, 0.f};
  f32x4 acc[2][4];
#pragma unroll
  for (int i = 0; i < 2; ++i)
#pragma unroll
    for (int j = 0; j < 4; ++j) acc[i][j] = z4;

  auto load_chunk = [&](int ch, s16x8 af[2], s16x8 bf_[4]) {
#pragma unroll
    for (int i = 0; i < 2; ++i) {
      const int row = r0 + (wr * 2 + i) * 16 + lm;
      s16x8 a = (s16x8)0;
      if (row < M) {
        const float4 f0 = *reinterpret_cast<const float4*>(&x[(size_t)row * 512 + ch * 32 + lg * 8]);
        const float4 f1 = *reinterpret_cast<const float4*>(&x[(size_t)row * 512 + ch * 32 + lg * 8 + 4]);
        a[0] = (short)f2bfh(f0.x); a[1] = (short)f2bfh(f0.y);
        a[2] = (short)f2bfh(f0.z); a[3] = (short)f2bfh(f0.w);
        a[4] = (short)f2bfh(f1.x); a[5] = (short)f2bfh(f1.y);
        a[6] = (short)f2bfh(f1.z); a[7] = (short)f2bfh(f1.w);
      }
      af[i] = a;
    }
#pragma unroll
    for (int j = 0; j < 4; ++j) {
      const int n = (wc * 4 + j) * 16 + lm;
      bf_[j] = *reinterpret_cast<const s16x8*>(&WT[(size_t)n * 512 + ch * 32 + lg * 8]);
    }
  };

  s16x8 af[2], bf_[4];
  load_chunk(0, af, bf_);
  for (int ch = 0; ch < 16; ++ch) {
    s16x8 naf[2], nbf[4];
    if (ch < 15) load_chunk(ch + 1, naf, nbf);
#pragma unroll
    for (int i = 0; i < 2; ++i)
#pragma unroll
      for (int j = 0; j < 4; ++j)
        acc[i][j] = __builtin_amdgcn_mfma_f32_16x16x32_bf16(af[i], bf_[j], acc[i][j], 0, 0, 0);
    if (ch < 15) {
#pragma unroll
      for (int i = 0; i < 2; ++i) af[i] = naf[i];
#pragma unroll
      for (int j = 0; j < 4; ++j) bf_[j] = nbf[j];
    }
  }

#pragma unroll
  for (int i = 0; i < 2; ++i) {
#pragma unroll
    for (int rr = 0; rr < 4; ++rr) {
      const int row = r0 + (wr * 2 + i) * 16 + lg * 4 + rr;
      if (row < M) {
#pragma unroll
        for (int j = 0; j < 4; ++j)
          C[(size_t)row * 128 + (wc * 4 + j) * 16 + lm] = acc[i][j][rr];
      }
    }
  }
}

// ------- MFMA fused 16->128->128 MLP over bf16 rows -------
// 64 rows/block, 4 waves = 4 col-quadrants. 16KB LDS.
// MODE 0: exp2 -> fp8 byte LDS (R15 layout) -> u32 coalesced copy-out.
// MODE 1: lrelu(0.01) -> bf16 via LDS coalesced stores.
template <int MODE>
__global__ __launch_bounds__(256) void k_emlp(
    const u16* __restrict__ inp,              // [R][16] bf16
    const u16* __restrict__ WaTg, const u16* __restrict__ WbTg,
    const float* __restrict__ bbias,
    void* __restrict__ outp, int R) {
  __shared__ __align__(16) unsigned char sU[16384];
  const int tid = threadIdx.x;
  const int lane = tid & 63;
  const int wc = tid >> 6;   // 0..3 col quadrant
  const int lg = lane >> 4;
  const int lm = lane & 15;
  const int r0 = blockIdx.x * 64;

  s16x8 afr[4];
#pragma unroll
  for (int i = 0; i < 4; ++i) {
    s16x8 a = (s16x8)0;
    if (lg < 2) {
      const int r = r0 + i * 16 + lm;
      if (r < R) a = *reinterpret_cast<const s16x8*>(&inp[(size_t)r * 16 + lg * 8]);
    }
    afr[i] = a;
  }

  const f32x4 z4 = {0.f, 0.f, 0.f, 0.f};
  s16x8 bfr1[2];
#pragma unroll
  for (int j = 0; j < 2; ++j) {
    s16x8 b = (s16x8)0;
    if (lg < 2) {
      const int n = wc * 32 + j * 16 + lm;
      b = *reinterpret_cast<const s16x8*>(&WaTg[n * 16 + lg * 8]);
    }
    bfr1[j] = b;
  }

  f32x4 acc1[4][2];
#pragma unroll
  for (int i = 0; i < 4; ++i)
#pragma unroll
    for (int j = 0; j < 2; ++j) acc1[i][j] = z4;
#pragma unroll
  for (int i = 0; i < 4; ++i)
#pragma unroll
    for (int j = 0; j < 2; ++j)
      acc1[i][j] = __builtin_amdgcn_mfma_f32_16x16x32_bf16(afr[i], bfr1[j], acc1[i][j], 0, 0, 0);

#pragma unroll
  for (int i = 0; i < 4; ++i) {
#pragma unroll
    for (int j = 0; j < 2; ++j) {
#pragma unroll
      for (int rr = 0; rr < 4; ++rr) {
        float v = acc1[i][j][rr];
        v = (v >= 0.f) ? v : 0.2f * v;
        const int grow = i * 16 + lg * 4 + rr;
        const int gcol = wc * 32 + j * 16 + lm;
        const int byte = grow * 256 + ((((gcol >> 3) ^ (grow & 15))) << 4) + (gcol & 7) * 2;
        *reinterpret_cast<u16*>(&sU[byte]) = f2bfh(v);
      }
    }
  }
  __syncthreads();

  f32x4 acc[4][2];
#pragma unroll
  for (int i = 0; i < 4; ++i)
#pragma unroll
    for (int j = 0; j < 2; ++j) acc[i][j] = z4;
#pragma unroll
  for (int kb = 0; kb < 4; ++kb) {
    s16x8 af[4], bf_[2];
    const int ch = kb * 4 + lg;
#pragma unroll
    for (int j = 0; j < 2; ++j) {
      const int n = wc * 32 + j * 16 + lm;
      bf_[j] = *reinterpret_cast<const s16x8*>(&WbTg[n * 128 + ch * 8]);
    }
#pragma unroll
    for (int i = 0; i < 4; ++i) {
      const int row = i * 16 + lm;
      af[i] = *reinterpret_cast<const s16x8*>(&sU[row * 256 + ((ch ^ (row & 15)) << 4)]);
    }
#pragma unroll
    for (int i = 0; i < 4; ++i)
#pragma unroll
      for (int j = 0; j < 2; ++j)
        acc[i][j] = __builtin_amdgcn_mfma_f32_16x16x32_bf16(af[i], bf_[j], acc[i][j], 0, 0, 0);
  }
  __syncthreads();  // done reading sU; safe to overwrite

  float bv[2];
#pragma unroll
  for (int j = 0; j < 2; ++j) bv[j] = bbias[wc * 32 + j * 16 + lm];

  if (MODE == 0) {
    // fp8 epilogue (R15 layout): byte = row*128 + (c ^ (((row>>2)&3)<<2))
#pragma unroll
    for (int i = 0; i < 4; ++i) {
#pragma unroll
      for (int rr = 0; rr < 4; ++rr) {
        const float v0 = exp2f(acc[i][0][rr] + bv[0]);
        const float v1 = exp2f(acc[i][1][rr] + bv[1]);
        const u32 pk = f2e4m3_pair(v0, v1);
        const int grow = i * 16 + lg * 4 + rr;
        const int gc0 = wc * 32 + lm;
        const int gc1 = gc0 + 16;
        const int sw = ((grow >> 2) & 3) << 2;
        sU[grow * 128 + (gc0 ^ sw)] = (u8)(pk & 0xffu);
        sU[grow * 128 + (gc1 ^ sw)] = (u8)(pk >> 8);
      }
    }
    __syncthreads();
    u8* o8 = (u8*)outp;
    const int rmax = R - r0;
#pragma unroll
    for (int q = 0; q < 8; ++q) {
      const int u = tid + q * 256;
      const int row = u >> 5, c4s = u & 31;
      if (row < rmax) {
        const u32 v = *reinterpret_cast<const u32*>(&sU[row * 128 + c4s * 4]);
        const int c4 = c4s ^ ((row >> 2) & 3);
        *reinterpret_cast<u32*>(&o8[(size_t)(r0 + row) * 128 + c4 * 4]) = v;
      }
    }
  } else {
#pragma unroll
    for (int i = 0; i < 4; ++i) {
#pragma unroll
      for (int j = 0; j < 2; ++j) {
#pragma unroll
        for (int rr = 0; rr < 4; ++rr) {
          float v = acc[i][j][rr] + bv[j];
          v = (v >= 0.f) ? v : 0.01f * v;
          const int grow = i * 16 + lg * 4 + rr;
          const int gcol = wc * 32 + j * 16 + lm;
          const int byte = grow * 256 + ((((gcol >> 3) ^ (grow & 15))) << 4) + (gcol & 7) * 2;
          *reinterpret_cast<u16*>(&sU[byte]) = f2bfh(v);
        }
      }
    }
    __syncthreads();
    u16* o16 = (u16*)outp;
    const int rmax = R - r0;
#pragma unroll
    for (int q = 0; q < 4; ++q) {
      const int u = tid + q * 256;
      const int row = u >> 4, c8 = u & 15;
      if (row < rmax) {
        const uint4 v = *reinterpret_cast<const uint4*>(&sU[row * 256 + ((c8 ^ (row & 15)) << 4)]);
        *reinterpret_cast<uint4*>(&o16[(size_t)(r0 + row) * 128 + c8 * 8]) = v;
      }
    }
  }
}

// ------- MFMA fused 16->40->40 MLP (48-padded), bf16 out -------
template <int MODE>
__global__ __launch_bounds__(256) void k_emlp48(
    const u16* __restrict__ inp,              // [R][16] bf16
    const u16* __restrict__ WaT,              // [48][16]
    const u16* __restrict__ WbT,              // [48][64]
    const float* __restrict__ bias48,         // [48]
    u16* __restrict__ outp, int R) {          // [R][40] bf16
  __shared__ __align__(16) unsigned char sU[16384];
  const int tid = threadIdx.x;
  const int lane = tid & 63;
  const int wv = tid >> 6;
  const int lg = lane >> 4;
  const int lm = lane & 15;
  const int r0 = blockIdx.x * 128;

#pragma unroll
  for (int q = 0; q < 4; ++q) {
    const int u = tid + q * 256;
    const int row = u >> 3;
    const int col = 48 + (u & 7) * 2;
    const int byte = row * 128 + ((((col >> 3) ^ (row & 7))) << 4) + (col & 7) * 2;
    *reinterpret_cast<u32*>(&sU[byte]) = 0;
  }

  s16x8 afr[2];
#pragma unroll
  for (int i = 0; i < 2; ++i) {
    s16x8 a = (s16x8)0;
    if (lg < 2) {
      const int r = r0 + wv * 32 + i * 16 + lm;
      if (r < R) a = *reinterpret_cast<const s16x8*>(&inp[(size_t)r * 16 + lg * 8]);
    }
    afr[i] = a;
  }
  const f32x4 z4 = {0.f, 0.f, 0.f, 0.f};
  s16x8 bfr1[3];
#pragma unroll
  for (int j = 0; j < 3; ++j) {
    s16x8 b = (s16x8)0;
    if (lg < 2) {
      const int n = j * 16 + lm;
      b = *reinterpret_cast<const s16x8*>(&WaT[n * 16 + lg * 8]);
    }
    bfr1[j] = b;
  }
  f32x4 acc1[2][3];
#pragma unroll
  for (int i = 0; i < 2; ++i)
#pragma unroll
    for (int j = 0; j < 3; ++j) acc1[i][j] = z4;
#pragma unroll
  for (int i = 0; i < 2; ++i)
#pragma unroll
    for (int j = 0; j < 3; ++j)
      acc1[i][j] = __builtin_amdgcn_mfma_f32_16x16x32_bf16(afr[i], bfr1[j], acc1[i][j], 0, 0, 0);

#pragma unroll
  for (int i = 0; i < 2; ++i) {
#pragma unroll
    for (int j = 0; j < 3; ++j) {
#pragma unroll
      for (int rr = 0; rr < 4; ++rr) {
        float v = acc1[i][j][rr];
        v = (v >= 0.f) ? v : 0.2f * v;
        const int grow = wv * 32 + i * 16 + lg * 4 + rr;
        const int gcol = j * 16 + lm;
        const int byte = grow * 128 + ((((gcol >> 3) ^ (grow & 7))) << 4) + (gcol & 7) * 2;
        *reinterpret_cast<u16*>(&sU[byte]) = f2bfh(v);
      }
    }
  }
  __syncthreads();

  f32x4 acc[2][3];
#pragma unroll
  for (int i = 0; i < 2; ++i)
#pragma unroll
    for (int j = 0; j < 3; ++j) acc[i][j] = z4;
#pragma unroll
  for (int kb = 0; kb < 2; ++kb) {
    s16x8 af[2], bf_[3];
    const int ch = kb * 4 + lg;
#pragma unroll
    for (int j = 0; j < 3; ++j) {
      const int n = j * 16 + lm;
      bf_[j] = *reinterpret_cast<const s16x8*>(&WbT[n * 64 + ch * 8]);
    }
#pragma unroll
    for (int i = 0; i < 2; ++i) {
      const int row = wv * 32 + i * 16 + lm;
      af[i] = *reinterpret_cast<const s16x8*>(&sU[row * 128 + ((ch ^ (row & 7)) << 4)]);
    }
#pragma unroll
    for (int i = 0; i < 2; ++i)
#pragma unroll
      for (int j = 0; j < 3; ++j)
        acc[i][j] = __builtin_amdgcn_mfma_f32_16x16x32_bf16(af[i], bf_[j], acc[i][j], 0, 0, 0);
  }
  __syncthreads();

  float bv[3];
#pragma unroll
  for (int j = 0; j < 3; ++j) bv[j] = bias48[j * 16 + lm];
#pragma unroll
  for (int i = 0; i < 2; ++i) {
#pragma unroll
    for (int j = 0; j < 3; ++j) {
#pragma unroll
      for (int rr = 0; rr < 4; ++rr) {
        float v = acc[i][j][rr] + bv[j];
        if (MODE == 0) v = __expf(v);
        else v = (v >= 0.f) ? v : 0.01f * v;
        const int grow = wv * 32 + i * 16 + lg * 4 + rr;
        const int gcol = j * 16 + lm;
        const int byte = grow * 128 + ((((gcol >> 3) ^ (grow & 7))) << 4) + (gcol & 7) * 2;
        *reinterpret_cast<u16*>(&sU[byte]) = f2bfh(v);
      }
    }
  }
  __syncthreads();

  const int rmax = R - r0;
  const int row = tid >> 1, half = tid & 1;
  if (row < rmax) {
    const size_t obase = (size_t)(r0 + row) * 40;
#pragma unroll
    for (int q = 0; q < 10; ++q) {
      const int col = (half * 10 + q) * 2;
      const int byte = row * 128 + ((((col >> 3) ^ (row & 7))) << 4) + (col & 7) * 2;
      *reinterpret_cast<u32*>(&outp[obase + col]) = *reinterpret_cast<const u32*>(&sU[byte]);
    }
  }
}

// ------------- h2 = y1 @ W2  [M,128]@[128,40] ----------
__global__ __launch_bounds__(256) void k_gemm2(const float* __restrict__ A,
                                               const float* __restrict__ B,
                                               float* __restrict__ C, int M) {
  __shared__ float Bs[128 * 40];
  const int tid = threadIdx.x;
  for (int i = tid; i < 5120; i += 256) Bs[i] = B[i];
  __syncthreads();
  const int r = blockIdx.x * 6 + tid / 40;
  const int c = tid % 40;
  if (tid >= 240 || r >= M) return;
  const float* arow = &A[(size_t)r * 128];
  float acc = 0.f;
#pragma unroll
  for (int k4 = 0; k4 < 32; ++k4) {
    const float4 av = *reinterpret_cast<const float4*>(&arow[k4 * 4]);
    acc = fmaf(av.x, Bs[(k4 * 4 + 0) * 40 + c], acc);
    acc = fmaf(av.y, Bs[(k4 * 4 + 1) * 40 + c], acc);
    acc = fmaf(av.z, Bs[(k4 * 4 + 2) * 40 + c], acc);
    acc = fmaf(av.w, Bs[(k4 * 4 + 3) * 40 + c], acc);
  }
  C[(size_t)r * 40 + c] = acc;
}

// ================= CSR build =================
__global__ __launch_bounds__(256) void k_hist(const int* __restrict__ src,
                                              const int* __restrict__ dst,
                                              int* __restrict__ cnt, int N, int E) {
  const int e = blockIdx.x * 256 + threadIdx.x;
  if (e >= E) return;
  atomicAdd(&cnt[src[e]], 1);
  atomicAdd(&cnt[N + dst[e]], 1);
}

__global__ __launch_bounds__(256) void k_scanA(const int* __restrict__ cnt,
                                               int* __restrict__ bsum, int N, int NB) {
  const int arr = blockIdx.x / NB, bb = blockIdx.x % NB;
  const int g = bb * 256 + threadIdx.x;
  int v = (g < N) ? cnt[arr * N + g] : 0;
  __shared__ int sd[256];
  sd[threadIdx.x] = v;
  __syncthreads();
  for (int off = 128; off > 0; off >>= 1) {
    if (threadIdx.x < off) sd[threadIdx.x] += sd[threadIdx.x + off];
    __syncthreads();
  }
  if (threadIdx.x == 0) bsum[arr * 256 + bb] = sd[0];
}

__global__ __launch_bounds__(256) void k_scanB(const int* __restrict__ bsum,
                                               int* __restrict__ boff, int NB) {
  __shared__ int sd[256];
  for (int arr = 0; arr < 2; ++arr) {
    const int v = (threadIdx.x < NB) ? bsum[arr * 256 + threadIdx.x] : 0;
    sd[threadIdx.x] = v;
    __syncthreads();
    for (int off = 1; off < 256; off <<= 1) {
      const int t = (threadIdx.x >= off) ? sd[threadIdx.x - off] : 0;
      __syncthreads();
      sd[threadIdx.x] += t;
      __syncthreads();
    }
    if (threadIdx.x < NB) boff[arr * 256 + threadIdx.x] = sd[threadIdx.x] - v;
    __syncthreads();
  }
}

__global__ __launch_bounds__(256) void k_scanC(const int* __restrict__ cnt,
                                               const int* __restrict__ boff,
                                               int* __restrict__ row_src,
                                               int* __restrict__ row_dst,
                                               int* __restrict__ cur, int N, int NB) {
  const int arr = blockIdx.x / NB, bb = blockIdx.x % NB;
  const int g = bb * 256 + threadIdx.x;
  const int v = (g < N) ? cnt[arr * N + g] : 0;
  __shared__ int sd[256];
  sd[threadIdx.x] = v;
  __syncthreads();
  for (int off = 1; off < 256; off <<= 1) {
    const int t = (threadIdx.x >= off) ? sd[threadIdx.x - off] : 0;
    __syncthreads();
    sd[threadIdx.x] += t;
    __syncthreads();
  }
  const int incl = sd[threadIdx.x];
  const int base = boff[arr * 256 + bb];
  int* row = arr ? row_dst : row_src;
  if (g < N) {
    row[g] = base + incl - v;
    cur[arr * N + g] = base + incl - v;
    if (g == N - 1) row[N] = base + incl;
  }
}

// per-edge: ps = src-order position, pd = dst-order position.
__global__ __launch_bounds__(256) void k_scatter(const int* __restrict__ src,
                                                 const int* __restrict__ dst,
                                                 int* __restrict__ cur,
                                                 const float* __restrict__ kric,
                                                 u16* __restrict__ kricP,
                                                 uint2* __restrict__ pdInfo, int N, int E) {
  const int e = blockIdx.x * 256 + threadIdx.x;
  if (e >= E) return;
  const int s = src[e], d = dst[e];
  const float4 f0 = *reinterpret_cast<const float4*>(&kric[(size_t)e * 16]);
  const float4 f1 = *reinterpret_cast<const float4*>(&kric[(size_t)e * 16 + 4]);
  const float4 f2 = *reinterpret_cast<const float4*>(&kric[(size_t)e * 16 + 8]);
  const float4 f3 = *reinterpret_cast<const float4*>(&kric[(size_t)e * 16 + 12]);
  const int ps = atomicAdd(&cur[s], 1);
  const int pd = atomicAdd(&cur[N + d], 1);
  pdInfo[pd] = make_uint2((u32)ps, (u32)s);
  u32 pk[8];
  pk[0] = (u32)f2bfh(f0.x) | ((u32)f2bfh(f0.y) << 16);
  pk[1] = (u32)f2bfh(f0.z) | ((u32)f2bfh(f0.w) << 16);
  pk[2] = (u32)f2bfh(f1.x) | ((u32)f2bfh(f1.y) << 16);
  pk[3] = (u32)f2bfh(f1.z) | ((u32)f2bfh(f1.w) << 16);
  pk[4] = (u32)f2bfh(f2.x) | ((u32)f2bfh(f2.y) << 16);
  pk[5] = (u32)f2bfh(f2.z) | ((u32)f2bfh(f2.w) << 16);
  pk[6] = (u32)f2bfh(f3.x) | ((u32)f2bfh(f3.y) << 16);
  pk[7] = (u32)f2bfh(f3.z) | ((u32)f2bfh(f3.w) << 16);
  u16* outr = &kricP[(size_t)ps * 16];
  *reinterpret_cast<uint4*>(outr) = make_uint4(pk[0], pk[1], pk[2], pk[3]);
  *reinterpret_cast<uint4*>(outr + 8) = make_uint4(pk[4], pk[5], pk[6], pk[7]);
}

// ===== layer1: s = segsum(fp8 ew rows [r0,r1)), gB = bf16(h/(s+eps)) =====
__global__ __launch_bounds__(256) void k_norm128f8(const int* __restrict__ rowp,
                                                   const u8* __restrict__ ew8,
                                                   const float* __restrict__ h,
                                                   u16* __restrict__ gB, int N) {
  const int lane = threadIdx.x & 63;
  const int wv = threadIdx.x >> 6;
  const int n = blockIdx.x * 4 + wv;
  if (n >= N) return;
  const int c0 = lane * 2;
  const int r0 = rowp[n], r1 = rowp[n + 1];
  float a0 = 0.f, a1 = 0.f;
  int p = r0;
  for (; p + 2 <= r1; p += 2) {
    const u32 w0 = *reinterpret_cast<const u16*>(&ew8[(size_t)p * 128 + c0]);
    const u32 w1 = *reinterpret_cast<const u16*>(&ew8[(size_t)(p + 1) * 128 + c0]);
    a0 += e4m32f(w0 & 0xffu) + e4m32f(w1 & 0xffu);
    a1 += e4m32f(w0 >> 8) + e4m32f(w1 >> 8);
  }
  for (; p < r1; ++p) {
    const u32 w0 = *reinterpret_cast<const u16*>(&ew8[(size_t)p * 128 + c0]);
    a0 += e4m32f(w0 & 0xffu);
    a1 += e4m32f(w0 >> 8);
  }
  const float2 hv = *reinterpret_cast<const float2*>(&h[(size_t)n * 128 + c0]);
  const float gx = hv.x / (a0 + SM_EPS);
  const float gy = hv.y / (a1 + SM_EPS);
  *reinterpret_cast<u32*>(&gB[(size_t)n * 128 + c0]) = (u32)f2bfh(gx) | ((u32)f2bfh(gy) << 16);
}

// ===== layer1 agg: out = sum ew8[pd.x]*gB[pd.y] + b + alpha*pw, ELU =====
__global__ __launch_bounds__(256) void k_aggf128f8(const int* __restrict__ rowp,
                                                   const uint2* __restrict__ pdInfo,
                                                   const u8* __restrict__ ew8,
                                                   const u16* __restrict__ gB,
                                                   const u16* __restrict__ pw,
                                                   const float* __restrict__ bias,
                                                   const float* __restrict__ alpha_p,
                                                   float* __restrict__ out, int N) {
  const int lane = threadIdx.x & 63;
  const int wv = threadIdx.x >> 6;
  const int n = blockIdx.x * 4 + wv;
  if (n >= N) return;
  const int c0 = lane * 2;
  const int r0 = rowp[n], r1 = rowp[n + 1];
  float a0 = 0.f, a1 = 0.f;
  int p = r0;
  for (; p + 8 <= r1; p += 8) {
    uint2 ii[8];
    u32 ww[8];
    u32 gg[8];
#pragma unroll
    for (int t = 0; t < 8; ++t) ii[t] = pdInfo[p + t];
#pragma unroll
    for (int t = 0; t < 8; ++t) ww[t] = *reinterpret_cast<const u16*>(&ew8[(size_t)ii[t].x * 128 + c0]);
#pragma unroll
    for (int t = 0; t < 8; ++t) gg[t] = *reinterpret_cast<const u32*>(&gB[(size_t)ii[t].y * 128 + c0]);
#pragma unroll
    for (int t = 0; t < 8; ++t) {
      a0 = fmaf(e4m32f(ww[t] & 0xffu), bf2f((u16)(gg[t] & 0xffffu)), a0);
      a1 = fmaf(e4m32f(ww[t] >> 8), bf2f((u16)(gg[t] >> 16)), a1);
    }
  }
  for (; p < r1; ++p) {
    const uint2 i0 = pdInfo[p];
    const u32 w0 = *reinterpret_cast<const u16*>(&ew8[(size_t)i0.x * 128 + c0]);
    const u32 g0 = *reinterpret_cast<const u32*>(&gB[(size_t)i0.y * 128 + c0]);
    a0 = fmaf(e4m32f(w0 & 0xffu), bf2f((u16)(g0 & 0xffffu)), a0);
    a1 = fmaf(e4m32f(w0 >> 8), bf2f((u16)(g0 >> 16)), a1);
  }
  const float al = alpha_p[0];
  const u32 pv2 = *reinterpret_cast<const u32*>(&pw[(size_t)n * 128 + c0]);
  float v0 = a0 + bias[c0] + al * bf2f((u16)(pv2 & 0xffffu));
  float v1 = a1 + bias[c0 + 1] + al * bf2f((u16)(pv2 >> 16));
  v0 = (v0 > 0.f) ? v0 : expm1f(v0);
  v1 = (v1 > 0.f) ? v1 : expm1f(v1);
  *reinterpret_cast<float2*>(&out[(size_t)n * 128 + c0]) = make_float2(v0, v1);
}

// ===== layer2 (bf16 ew, C=40): s = segsum, gB = bf16(h/(s+eps)) =====
__global__ __launch_bounds__(256) void k_norm40(const int* __restrict__ rowp,
                                                const u16* __restrict__ ew,
                                                const float* __restrict__ h,
                                                u16* __restrict__ gB, int N) {
  const int lane = threadIdx.x & 63;
  const int wv = threadIdx.x >> 6;
  const int n = blockIdx.x * 4 + wv;
  if (n >= N) return;
  const int c0 = lane;
  if (c0 >= 40) return;
  const int r0 = rowp[n], r1 = rowp[n + 1];
  float a0 = 0.f;
  int p = r0;
  for (; p + 2 <= r1; p += 2)
    a0 += bf2f(ew[(size_t)p * 40 + c0]) + bf2f(ew[(size_t)(p + 1) * 40 + c0]);
  for (; p < r1; ++p) a0 += bf2f(ew[(size_t)p * 40 + c0]);
  gB[(size_t)n * 40 + c0] = f2bfh(h[(size_t)n * 40 + c0] / (a0 + SM_EPS));
}

__global__ __launch_bounds__(256) void k_aggf40(const int* __restrict__ rowp,
                                                const uint2* __restrict__ pdInfo,
                                                const u16* __restrict__ ew,
                                                const u16* __restrict__ gB,
                                                const u16* __restrict__ pw,
                                                const float* __restrict__ bias,
                                                const float* __restrict__ alpha_p,
                                                float* __restrict__ out, int N) {
  const int lane = threadIdx.x & 63;
  const int wv = threadIdx.x >> 6;
  const int n = blockIdx.x * 4 + wv;
  if (n >= N) return;
  const int c0 = lane;
  if (c0 >= 40) return;
  const int r0 = rowp[n], r1 = rowp[n + 1];
  float a0 = 0.f;
  int p = r0;
  for (; p + 4 <= r1; p += 4) {
    const uint2 i0 = pdInfo[p + 0], i1 = pdInfo[p + 1], i2 = pdInfo[p + 2], i3 = pdInfo[p + 3];
    const float w0 = bf2f(ew[(size_t)i0.x * 40 + c0]);
    const float w1 = bf2f(ew[(size_t)i1.x * 40 + c0]);
    const float w2 = bf2f(ew[(size_t)i2.x * 40 + c0]);
    const float w3 = bf2f(ew[(size_t)i3.x * 40 + c0]);
    const float g0 = bf2f(gB[(size_t)i0.y * 40 + c0]);
    const float g1 = bf2f(gB[(size_t)i1.y * 40 + c0]);
    const float g2 = bf2f(gB[(size_t)i2.y * 40 + c0]);
    const float g3 = bf2f(gB[(size_t)i3.y * 40 + c0]);
    a0 = fmaf(w0, g0, a0);
    a0 = fmaf(w1, g1, a0);
    a0 = fmaf(w2, g2, a0);
    a0 = fmaf(w3, g3, a0);
  }
  for (; p < r1; ++p) {
    const uint2 i0 = pdInfo[p];
    a0 = fmaf(bf2f(ew[(size_t)i0.x * 40 + c0]), bf2f(gB[(size_t)i0.y * 40 + c0]), a0);
  }
  const float v = a0 + bias[c0] + alpha_p[0] * bf2f(pw[(size_t)n * 40 + c0]);
  out[(size_t)n * 40 + c0] = v;
}

extern "C" void kernel_launch(void* const* d_in, const int* in_sizes, int n_in,
                              void* d_out, int out_size, void* d_ws, size_t ws_size,
                              hipStream_t stream) {
  const float* x    = (const float*)d_in[0];
  const int*   ei   = (const int*)d_in[1];
  const float* kric = (const float*)d_in[2];
  const float* epoi = (const float*)d_in[3];
  const float* alpha= (const float*)d_in[4];
  const float* W1   = (const float*)d_in[5];
  const float* Wa1  = (const float*)d_in[6];
  const float* Wb1  = (const float*)d_in[7];
  const float* bb1  = (const float*)d_in[8];
  const float* Wc1  = (const float*)d_in[9];
  const float* Wd1  = (const float*)d_in[10];
  const float* bd1  = (const float*)d_in[11];
  const float* b1   = (const float*)d_in[12];
  const float* W2   = (const float*)d_in[13];
  const float* Wa2  = (const float*)d_in[14];
  const float* Wb2  = (const float*)d_in[15];
  const float* bb2  = (const float*)d_in[16];
  const float* Wc2  = (const float*)d_in[17];
  const float* Wd2  = (const float*)d_in[18];
  const float* bd2  = (const float*)d_in[19];
  const float* b2   = (const float*)d_in[20];

  const int N = in_sizes[0] / 512;
  const int E = in_sizes[1] / 2;
  const int* srcI = ei;
  const int* dstI = ei + E;
  const int NB = (N + 255) / 256;

  // ---- workspace layout ----
  char* p = (char*)d_ws;
  int* cnt      = (int*)p; p += (size_t)2 * N * 4;
  int* cur      = (int*)p; p += (size_t)2 * N * 4;
  int* bsum     = (int*)p; p += 512 * 4;
  int* boff     = (int*)p; p += 512 * 4;
  int* row_src  = (int*)p; p += (size_t)(N + 1) * 4;
  int* row_dst  = (int*)p; p += (size_t)(N + 1) * 4;
  p = (char*)(((uintptr_t)p + 255) & ~(uintptr_t)255);
  uint2* pdInfo = (uint2*)p; p += (size_t)E * 8;
  p = (char*)(((uintptr_t)p + 255) & ~(uintptr_t)255);
  u16* WaT1g = (u16*)p; p += 2048 * 2;
  u16* WbT1g = (u16*)p; p += 16384 * 2;
  u16* WcT1g = (u16*)p; p += 2048 * 2;
  u16* WdT1g = (u16*)p; p += 16384 * 2;
  u16* W1Tg  = (u16*)p; p += 65536 * 2;
  u16* WaT2g = (u16*)p; p += 768 * 2;
  u16* WbT2g = (u16*)p; p += 3072 * 2;
  u16* WcT2g = (u16*)p; p += 768 * 2;
  u16* WdT2g = (u16*)p; p += 3072 * 2;
  p = (char*)(((uintptr_t)p + 255) & ~(uintptr_t)255);
  float* bb48 = (float*)p; p += 48 * 4;
  float* bd48 = (float*)p; p += 48 * 4;
  float* bb1s = (float*)p; p += 128 * 4;
  p = (char*)(((uintptr_t)p + 255) & ~(uintptr_t)255);
  u16* kricP = (u16*)p; p += (size_t)E * 16 * 2;   // bf16, src-CSR order
  u16* epoiP = (u16*)p; p += (size_t)N * 16 * 2;   // bf16
  p = (char*)(((uintptr_t)p + 255) & ~(uintptr_t)255);
  float* h1  = (float*)p; p += (size_t)N * 128 * 4;
  u16* g1B   = (u16*)p;  p += (size_t)N * 128 * 2;   // bf16 normalized h1
  float* y1  = (float*)p; p += (size_t)N * 128 * 4;
  float* h2  = (float*)p; p += (size_t)N * 40 * 4;
  u16* g2B   = (u16*)p;  p += (size_t)N * 40 * 2;    // bf16 normalized h2
  u16* pw1   = (u16*)p;  p += (size_t)N * 128 * 2;   // bf16
  u16* pw2   = (u16*)p;  p += (size_t)N * 40 * 2;    // bf16
  p = (char*)(((uintptr_t)p + 255) & ~(uintptr_t)255);
  u8* ew8    = (u8*)p;   // layer1: E*128 fp8; layer2 reuses as E*40 bf16
  u16* ew40  = (u16*)p;

  // ---- CSR build + weight/input prep ----
  hipMemsetAsync(cnt, 0, (size_t)2 * N * 4, stream);
  k_prep<<<(110304 + 2 * N + 255) / 256, 256, 0, stream>>>(
      Wa1, Wb1, Wc1, Wd1, W1, Wa2, Wb2, Wc2, Wd2, bb2, bd2, bb1, epoi,
      WaT1g, WbT1g, WcT1g, WdT1g, W1Tg, WaT2g, WbT2g, WcT2g, WdT2g, bb48, bd48, bb1s, epoiP, N);
  k_hist<<<(E + 255) / 256, 256, 0, stream>>>(srcI, dstI, cnt, N, E);
  k_scanA<<<2 * NB, 256, 0, stream>>>(cnt, bsum, N, NB);
  k_scanB<<<1, 256, 0, stream>>>(bsum, boff, NB);
  k_scanC<<<2 * NB, 256, 0, stream>>>(cnt, boff, row_src, row_dst, cur, N, NB);
  k_scatter<<<(E + 255) / 256, 256, 0, stream>>>(srcI, dstI, cur, kric, kricP, pdInfo, N, E);

  // ---------------- layer 1 ----------------
  k_gemm1m<<<(N + 63) / 64, 256, 0, stream>>>(x, W1Tg, h1, N);
  k_emlp<0><<<(E + 63) / 64, 256, 0, stream>>>(kricP, WaT1g, WbT1g, bb1s, (void*)ew8, E);
  k_emlp<1><<<(N + 63) / 64, 256, 0, stream>>>(epoiP, WcT1g, WdT1g, bd1, (void*)pw1, N);
  k_norm128f8<<<(N + 3) / 4, 256, 0, stream>>>(row_src, ew8, h1, g1B, N);
  k_aggf128f8<<<(N + 3) / 4, 256, 0, stream>>>(row_dst, pdInfo, ew8, g1B, pw1, b1, alpha, y1, N);

  // ---------------- layer 2 ----------------
  k_gemm2<<<(N + 5) / 6, 256, 0, stream>>>(y1, W2, h2, N);
  k_emlp48<0><<<(E + 127) / 128, 256, 0, stream>>>(kricP, WaT2g, WbT2g, bb48, ew40, E);
  k_emlp48<1><<<(N + 127) / 128, 256, 0, stream>>>(epoiP, WcT2g, WdT2g, bd48, pw2, N);
  k_norm40<<<(N + 3) / 4, 256, 0, stream>>>(row_src, ew40, h2, g2B, N);
  k_aggf40<<<(N + 3) / 4, 256, 0, stream>>>(row_dst, pdInfo, ew40, g2B, pw2, b2, alpha, (float*)d_out, N);
}